// Round 8
// baseline (282.184 us; speedup 1.0000x reference)
//
#include <hip/hip_runtime.h>
#include <stdint.h>

#define BATCH 4096

typedef float v16f __attribute__((ext_vector_type(16)));
typedef short v8s  __attribute__((ext_vector_type(8)));

__device__ __forceinline__ int sgn8(float v) {
    return (v > 0.f) ? 1 : ((v < 0.f) ? -1 : 0);
}

// ---------------------------------------------------------------------------
// sign(w) -> bf16 MFMA B-fragment layout (used for BOTH w1 and w2):
// o[tp*1024 + kh*512 + q*256 + n*8 + j] = sign(w[n][kh*16+q*8+j][tp]) as bf16
// ---------------------------------------------------------------------------
__global__ void k_signw1(const float* __restrict__ w, uint16_t* __restrict__ o) {
    int i = blockIdx.x * 256 + threadIdx.x;
    if (i >= 9216) return;
    int j = i & 7, n = (i >> 3) & 31, q = (i >> 8) & 1, kh = (i >> 9) & 1, tp = i >> 10;
    int cin = kh * 16 + q * 8 + j;
    float v = w[(n * 32 + cin) * 9 + tp];
    o[i] = (v > 0.f) ? 0x3F80 : ((v < 0.f) ? 0xBF80 : 0);
}

// ---------------------------------------------------------------------------
// conv0: fp32 1->32ch 3x3 pad1 on 28x28 + maxpool2 -> p0 [B][32][14][14],
// fused per-channel double stats.  448 threads: thread = (c = t/14, py = t%14)
// owns one pooled row of 14 windows, sliding aligned float4 chunks.
// xs padded to 32-col stride so all float4 reads are aligned; cols 29..31
// and row 0/29 are the zero halo.  part0 layout: [c*4096+n] (+32*4096 for sq)
// so k_finalize reads are contiguous per channel.
// ---------------------------------------------------------------------------
__global__ __launch_bounds__(448) void k_conv0(const float* __restrict__ x,
                                               const float* __restrict__ w0,
                                               float* __restrict__ p0,
                                               double* __restrict__ part0) {
    __shared__ float xs[960];   // 30 rows x 32 cols
    __shared__ float wl[288];
    __shared__ double rs[32][14], rq[32][14];
    int n = blockIdx.x, t = threadIdx.x;
    for (int i = t; i < 960; i += 448) xs[i] = 0.f;
    for (int i = t; i < 288; i += 448) wl[i] = w0[i];
    __syncthreads();
    for (int i = t; i < 784; i += 448) {
        int y = i / 28, xx = i - y * 28;
        xs[(y + 1) * 32 + xx + 1] = x[n * 784 + i];
    }
    __syncthreads();
    int c = t / 14, py = t - c * 14;
    float wreg[9];
    #pragma unroll
    for (int i = 0; i < 9; ++i) wreg[i] = wl[c * 9 + i];
    const float4* X4 = (const float4*)xs;
    float4 cur0 = X4[(2 * py + 0) * 8];
    float4 cur1 = X4[(2 * py + 1) * 8];
    float4 cur2 = X4[(2 * py + 2) * 8];
    float4 cur3 = X4[(2 * py + 3) * 8];
    double s = 0.0, q = 0.0;
    float* orow = p0 + n * 6272 + c * 196 + py * 14;
    #pragma unroll
    for (int k = 0; k < 7; ++k) {
        float4 n0 = X4[(2 * py + 0) * 8 + k + 1];
        float4 n1 = X4[(2 * py + 1) * 8 + k + 1];
        float4 n2 = X4[(2 * py + 2) * 8 + k + 1];
        float4 n3 = X4[(2 * py + 3) * 8 + k + 1];
        float a[4][6];
        a[0][0] = cur0.x; a[0][1] = cur0.y; a[0][2] = cur0.z; a[0][3] = cur0.w; a[0][4] = n0.x; a[0][5] = n0.y;
        a[1][0] = cur1.x; a[1][1] = cur1.y; a[1][2] = cur1.z; a[1][3] = cur1.w; a[1][4] = n1.x; a[1][5] = n1.y;
        a[2][0] = cur2.x; a[2][1] = cur2.y; a[2][2] = cur2.z; a[2][3] = cur2.w; a[2][4] = n2.x; a[2][5] = n2.y;
        a[3][0] = cur3.x; a[3][1] = cur3.y; a[3][2] = cur3.z; a[3][3] = cur3.w; a[3][4] = n3.x; a[3][5] = n3.y;
        #pragma unroll
        for (int e = 0; e < 2; ++e) {
            int base = 2 * e;
            float s00 = 0.f, s01 = 0.f, s10 = 0.f, s11 = 0.f;
            #pragma unroll
            for (int ky = 0; ky < 3; ++ky)
            #pragma unroll
            for (int kx = 0; kx < 3; ++kx) {
                float w = wreg[ky * 3 + kx];
                s00 = fmaf(a[ky][base + kx], w, s00);
                s01 = fmaf(a[ky][base + kx + 1], w, s01);
                s10 = fmaf(a[ky + 1][base + kx], w, s10);
                s11 = fmaf(a[ky + 1][base + kx + 1], w, s11);
            }
            float m = fmaxf(fmaxf(s00, s01), fmaxf(s10, s11));
            orow[2 * k + e] = m;
            double v = (double)m;
            s += v; q += v * v;
        }
        cur0 = n0; cur1 = n1; cur2 = n2; cur3 = n3;
    }
    rs[c][py] = s; rq[c][py] = q;
    __syncthreads();
    if (t < 32) {
        double S = 0.0, Q = 0.0;
        #pragma unroll
        for (int i = 0; i < 14; ++i) { S += rs[t][i]; Q += rq[t][i]; }
        part0[(size_t)t * 4096 + n] = S;
        part0[(size_t)32 * 4096 + (size_t)t * 4096 + n] = Q;
    }
}

// ---------------------------------------------------------------------------
// finalize: grid(32) x 256 threads. Block = channel. Fixed-order reduction
// of G partials, layout part[c*G+i] (sums) / part[32G + c*G+i] (sumsq) --
// contiguous per channel => coalesced. double math; deterministic.
// ---------------------------------------------------------------------------
__global__ __launch_bounds__(256) void k_finalize(const double* __restrict__ part, int G,
                                                  const float* __restrict__ g,
                                                  const float* __restrict__ b,
                                                  double inv_count, float* __restrict__ ss) {
    int c = blockIdx.x, t = threadIdx.x;
    double s = 0.0, q = 0.0;
    for (int i = t; i < G; i += 256) {
        s += part[(size_t)c * G + i];
        q += part[(size_t)32 * G + (size_t)c * G + i];
    }
    #pragma unroll
    for (int o = 32; o > 0; o >>= 1) { s += __shfl_down(s, o); q += __shfl_down(q, o); }
    __shared__ double rs[4], rq[4];
    int w = t >> 6, l = t & 63;
    if (l == 0) { rs[w] = s; rq[w] = q; }
    __syncthreads();
    if (t == 0) {
        s = rs[0] + rs[1] + rs[2] + rs[3];
        q = rq[0] + rq[1] + rq[2] + rq[3];
        double mean = s * inv_count;
        double var = q * inv_count - mean * mean;
        double sc = (double)g[c] / sqrt(var + 1e-5);
        ss[c] = (float)sc;
        ss[32 + c] = (float)((double)b[c] - mean * sc);
    }
}

// ---------------------------------------------------------------------------
// bn0: block per image. p0 NCHW staged in LDS; writes s0 NHWC int8
// [n][196][32] and hp0 NHWC fp32 [n][49][32].
// ---------------------------------------------------------------------------
__global__ __launch_bounds__(256) void k_bn0(const float* __restrict__ p0,
                                             const float* __restrict__ ss,
                                             int8_t* __restrict__ s0,
                                             float* __restrict__ hp0) {
    __shared__ float P[6272];
    int n = blockIdx.x, t = threadIdx.x;
    const float* src = p0 + n * 6272;
    for (int i = t; i < 6272; i += 256) P[i] = src[i];
    __syncthreads();
    if (t < 196) {
        int p = t;
        uint32_t pk[8];
        #pragma unroll
        for (int cg = 0; cg < 8; ++cg) {
            uint32_t u = 0;
            #pragma unroll
            for (int k = 0; k < 4; ++k) {
                int c = cg * 4 + k;
                float v = fmaf(ss[c], P[c * 196 + p], ss[32 + c]);
                u |= ((uint32_t)(uint8_t)(int8_t)sgn8(v)) << (8 * k);
            }
            pk[cg] = u;
        }
        uint4* dst = (uint4*)(s0 + (size_t)n * 6272 + p * 32);
        uint4 v0; v0.x = pk[0]; v0.y = pk[1]; v0.z = pk[2]; v0.w = pk[3];
        uint4 v1; v1.x = pk[4]; v1.y = pk[5]; v1.z = pk[6]; v1.w = pk[7];
        dst[0] = v0; dst[1] = v1;

        int pw = t >> 2, oct = t & 3;           // 49 pw x 4 octs = 196
        int py = pw / 7, px = pw - py * 7;
        float out[8];
        #pragma unroll
        for (int k = 0; k < 8; ++k) {
            int c = oct * 8 + k;
            float sc = ss[c], sh = ss[32 + c];
            const float* B = &P[c * 196];
            float a0 = fmaf(sc, B[(2 * py) * 14 + 2 * px], sh);
            float a1 = fmaf(sc, B[(2 * py) * 14 + 2 * px + 1], sh);
            float a2 = fmaf(sc, B[(2 * py + 1) * 14 + 2 * px], sh);
            float a3 = fmaf(sc, B[(2 * py + 1) * 14 + 2 * px + 1], sh);
            out[k] = fmaxf(fmaxf(a0, a1), fmaxf(a2, a3));
        }
        float4* hd = (float4*)(hp0 + ((size_t)n * 49 + pw) * 32 + oct * 8);
        float4 h0; h0.x = out[0]; h0.y = out[1]; h0.z = out[2]; h0.w = out[3];
        float4 h1; h1.x = out[4]; h1.y = out[5]; h1.z = out[6]; h1.w = out[7];
        hd[0] = h0; hd[1] = h1;
    }
}

// ---------------------------------------------------------------------------
// conv1 bf16 MFMA implicit GEMM, 4 images/block, fused stats (G=1024,
// part layout [c*1024+b] / +32*1024 for sq).
// ---------------------------------------------------------------------------
__global__ __launch_bounds__(256) void k_conv1m(const int8_t* __restrict__ s0,
                                                const uint16_t* __restrict__ w1f,
                                                float* __restrict__ p1,
                                                double* __restrict__ part1) {
    __shared__ uint32_t lds[16384];   // 64 KB: 4 images x 256 pixels x 16 dwords
    int t = threadIdx.x;
    int n0 = blockIdx.x * 4;
    if (t < 240) {
        int img = t / 60, e = t % 60;
        int yh, xh;
        if (e < 16)      { yh = 0;      xh = e; }
        else if (e < 32) { yh = 15;     xh = e - 16; }
        else if (e < 46) { yh = e - 31; xh = 0; }
        else             { yh = e - 45; xh = 15; }
        uint32_t* d = &lds[img * 4096 + (yh * 16 + xh) * 16];
        uint4 z; z.x = z.y = z.z = z.w = 0u;
        ((uint4*)d)[0] = z; ((uint4*)d)[1] = z; ((uint4*)d)[2] = z; ((uint4*)d)[3] = z;
    }
    int lane = t & 63, wv = t >> 6;
    int q = lane >> 5, ncol = lane & 31;
    v8s wfr[18];
    #pragma unroll
    for (int f = 0; f < 18; ++f)
        wfr[f] = *(const v8s*)(w1f + (f * 2 + q) * 256 + ncol * 8);
    for (int i = t; i < 6272; i += 256) {
        int img = i / 1568, r = i - img * 1568;
        int pimg = r >> 3, dp = r & 7;
        int iy = pimg / 14, ix = pimg - iy * 14;
        int p = (iy + 1) * 16 + ix + 1;
        uint32_t u = ((const uint32_t*)s0)[(size_t)(n0 + img) * 1568 + r];
        uint32_t b0 = u & 0xFF, b1 = (u >> 8) & 0xFF, b2 = (u >> 16) & 0xFF, b3 = u >> 24;
        uint32_t h0 = b0 ? (0x3F80u | ((b0 & 0x80u) << 8)) : 0u;
        uint32_t h1 = b1 ? (0x3F80u | ((b1 & 0x80u) << 8)) : 0u;
        uint32_t h2 = b2 ? (0x3F80u | ((b2 & 0x80u) << 8)) : 0u;
        uint32_t h3 = b3 ? (0x3F80u | ((b3 & 0x80u) << 8)) : 0u;
        int g = dp >> 1;
        int gs = g ^ (p & 3);
        int idx = img * 4096 + p * 16 + (gs << 2) + ((dp & 1) << 1);
        lds[idx] = h0 | (h1 << 16);
        lds[idx + 1] = h2 | (h3 << 16);
    }
    __syncthreads();
    int n = n0 + wv;
    int ibase = wv * 4096;
    int m = lane & 31;
    int quad = m & 3, pwl = m >> 2;
    int dy = quad >> 1, dx = quad & 1;
    double sAcc = 0.0, qAcc = 0.0;
    for (int tile = 0; tile < 7; ++tile) {
        int pw = tile * 8 + pwl;
        int pwc = min(pw, 48);
        int py = pwc / 7, px = pwc - py * 7;
        int pbase = (2 * py + dy) * 16 + 2 * px + dx;
        v16f acc;
        #pragma unroll
        for (int i = 0; i < 16; ++i) acc[i] = 0.f;
        #pragma unroll
        for (int tp = 0; tp < 9; ++tp) {
            int p = pbase + (tp / 3) * 16 + (tp % 3);
            int psw = p & 3;
            #pragma unroll
            for (int kh = 0; kh < 2; ++kh) {
                int g = kh * 2 + q;
                int idx = ibase + p * 16 + ((g ^ psw) << 2);
                v8s a = *(const v8s*)&lds[idx];
                acc = __builtin_amdgcn_mfma_f32_32x32x16_bf16(a, wfr[tp * 2 + kh], acc, 0, 0, 0);
            }
        }
        #pragma unroll
        for (int g4 = 0; g4 < 4; ++g4) {
            float mx = fmaxf(fmaxf(acc[4 * g4], acc[4 * g4 + 1]),
                             fmaxf(acc[4 * g4 + 2], acc[4 * g4 + 3]));
            int pwo = tile * 8 + 2 * g4 + q;
            if (pwo < 49) {
                p1[((size_t)n * 49 + pwo) * 32 + ncol] = mx;
                double v = (double)mx;
                sAcc += v; qAcc += v * v;
            }
        }
    }
    __syncthreads();
    double* red = (double*)lds;   // act LDS dead; 512 doubles used
    red[(wv * 2 + q) * 32 + ncol] = sAcc;
    red[256 + (wv * 2 + q) * 32 + ncol] = qAcc;
    __syncthreads();
    if (t < 32) {
        double S = 0.0, Q = 0.0;
        #pragma unroll
        for (int i = 0; i < 8; ++i) { S += red[i * 32 + t]; Q += red[256 + i * 32 + t]; }
        part1[(size_t)t * 1024 + blockIdx.x] = S;
        part1[(size_t)32 * 1024 + (size_t)t * 1024 + blockIdx.x] = Q;
    }
}

// ---------------------------------------------------------------------------
// bn1: block per image. h = bn1(p1) + hp0 (both NHWC) in LDS; emits
// s1 NCHW-packed (for conv2m) and hp1 NCHW [n][c][9] (for FC).
// s1 image stride = 416 WORDS (32 ch x 13 words).
// ---------------------------------------------------------------------------
__global__ __launch_bounds__(256) void k_bn1(const float* __restrict__ p1,
                                             const float* __restrict__ hp0,
                                             const float* __restrict__ ss,
                                             uint32_t* __restrict__ s1,
                                             float* __restrict__ hp1) {
    __shared__ float H[1568];
    int n = blockIdx.x, t = threadIdx.x;
    const float* P = p1 + (size_t)n * 1568;
    const float* Hp = hp0 + (size_t)n * 1568;
    for (int i = t; i < 1568; i += 256) {
        int c = i & 31;
        H[i] = fmaf(ss[64 + c], P[i], ss[96 + c]) + Hp[i];
    }
    __syncthreads();
    if (t < 32) {
        int c = t;
        uint32_t* sp = s1 + (size_t)n * 416 + c * 13;
        for (int j = 0; j < 13; ++j) {
            uint32_t u = 0;
            #pragma unroll
            for (int k = 0; k < 4; ++k) {
                int f = 4 * j + k;
                int sv = (f < 49) ? sgn8(H[f * 32 + c]) : 0;
                u |= ((uint32_t)(uint8_t)(int8_t)sv) << (8 * k);
            }
            sp[j] = u;
        }
    }
    for (int jj = t; jj < 288; jj += 256) {
        int c = jj / 9, pix = jj - c * 9;
        int r = pix / 3, qq = pix - r * 3;
        float a0 = H[((2 * r) * 7 + 2 * qq) * 32 + c];
        float a1 = H[((2 * r) * 7 + 2 * qq + 1) * 32 + c];
        float a2 = H[((2 * r + 1) * 7 + 2 * qq) * 32 + c];
        float a3 = H[((2 * r + 1) * 7 + 2 * qq + 1) * 32 + c];
        hp1[n * 288 + c * 9 + pix] = fmaxf(fmaxf(a0, a1), fmaxf(a2, a3));
    }
}

// ---------------------------------------------------------------------------
// conv2 via bf16 MFMA implicit GEMM + fused stats. 8 images/block.
// part2 layout [c*512+b] / +32*512 for sq. p2 NCHW [n][32][9].
// ---------------------------------------------------------------------------
__global__ __launch_bounds__(256) void k_conv2m(const uint32_t* __restrict__ s1,
                                                const uint16_t* __restrict__ w2f,
                                                float* __restrict__ p2,
                                                double* __restrict__ part2) {
    __shared__ uint32_t lds[8192];   // 32 KB
    int t = threadIdx.x;
    int n0 = blockIdx.x * 8;
    for (int i = t; i < 120; i += 256) {
        int img = i / 15, e = i - img * 15;
        int p = (e < 8) ? e : (e - 7) * 8;
        uint32_t* d = &lds[img * 1024 + p * 16];
        uint4 z; z.x = z.y = z.z = z.w = 0u;
        ((uint4*)d)[0] = z; ((uint4*)d)[1] = z; ((uint4*)d)[2] = z; ((uint4*)d)[3] = z;
    }
    int lane = t & 63, wv = t >> 6;
    int q = lane >> 5, ncol = lane & 31;
    v8s wfr[18];
    #pragma unroll
    for (int f = 0; f < 18; ++f)
        wfr[f] = *(const v8s*)(w2f + (f * 2 + q) * 256 + ncol * 8);
    for (int i = t; i < 1664; i += 256) {
        int img = i / 208, r = i - img * 208;
        int c2 = r / 13, j = r - c2 * 13;
        const uint32_t* sb = s1 + (size_t)(n0 + img) * 416;
        uint32_t wa = sb[(2 * c2) * 13 + j];
        uint32_t wb = sb[(2 * c2 + 1) * 13 + j];
        int g = c2 >> 2, sub = c2 & 3;
        #pragma unroll
        for (int k = 0; k < 4; ++k) {
            int f = 4 * j + k;
            if (f < 49) {
                int y = f / 7, x = f - y * 7;
                int p = (y + 1) * 8 + (x + 1);
                uint32_t ba = (wa >> (8 * k)) & 0xFF;
                uint32_t bb = (wb >> (8 * k)) & 0xFF;
                uint32_t ha = ba ? (0x3F80u | ((ba & 0x80u) << 8)) : 0u;
                uint32_t hb = bb ? (0x3F80u | ((bb & 0x80u) << 8)) : 0u;
                lds[img * 1024 + p * 16 + ((g ^ (p & 3)) << 2) + sub] = ha | (hb << 16);
            }
        }
    }
    __syncthreads();
    int m = lane & 31;
    int quad = m & 3, pwl = m >> 2;
    int dy = quad >> 1, dx = quad & 1;
    double sAcc = 0.0, qAcc = 0.0;
    for (int tile = wv; tile < 9; tile += 4) {
        int pwg = tile * 8 + pwl;                    // 0..71
        int img = pwg / 9, pwi = pwg - img * 9;
        int py = pwi / 3, px = pwi - py * 3;
        int pbase = (2 * py + dy) * 8 + 2 * px + dx;
        v16f acc;
        #pragma unroll
        for (int i = 0; i < 16; ++i) acc[i] = 0.f;
        #pragma unroll
        for (int tp = 0; tp < 9; ++tp) {
            int p = pbase + (tp / 3) * 8 + (tp % 3);
            int psw = p & 3;
            #pragma unroll
            for (int kh = 0; kh < 2; ++kh) {
                int g = kh * 2 + q;
                int idx = img * 1024 + p * 16 + ((g ^ psw) << 2);
                v8s a = *(const v8s*)&lds[idx];
                acc = __builtin_amdgcn_mfma_f32_32x32x16_bf16(a, wfr[tp * 2 + kh], acc, 0, 0, 0);
            }
        }
        #pragma unroll
        for (int g4 = 0; g4 < 4; ++g4) {
            float mx = fmaxf(fmaxf(acc[4 * g4], acc[4 * g4 + 1]),
                             fmaxf(acc[4 * g4 + 2], acc[4 * g4 + 3]));
            int pwo = tile * 8 + 2 * g4 + q;          // 0..71
            int oimg = pwo / 9, opwi = pwo - oimg * 9;
            p2[(size_t)(n0 + oimg) * 288 + ncol * 9 + opwi] = mx;
            double v = (double)mx;
            sAcc += v; qAcc += v * v;
        }
    }
    __syncthreads();
    double* red = (double*)lds;   // act LDS dead; 512 doubles
    red[(wv * 2 + q) * 32 + ncol] = sAcc;
    red[256 + (wv * 2 + q) * 32 + ncol] = qAcc;
    __syncthreads();
    if (t < 32) {
        double S = 0.0, Q = 0.0;
        #pragma unroll
        for (int i = 0; i < 8; ++i) { S += red[i * 32 + t]; Q += red[256 + i * 32 + t]; }
        part2[(size_t)t * 512 + blockIdx.x] = S;
        part2[(size_t)32 * 512 + (size_t)t * 512 + blockIdx.x] = Q;
    }
}

// ---------------------------------------------------------------------------
// FC: out[n,k] = sum_j (bn2(p2)+hp1)[n,j] * fw[k,j] + fb[k].  Wave per image.
// ---------------------------------------------------------------------------
__global__ __launch_bounds__(256) void k_fc(const float* __restrict__ p2,
                                            const float* __restrict__ hp1,
                                            const float* __restrict__ ss,
                                            const float* __restrict__ fw,
                                            const float* __restrict__ fb,
                                            float* __restrict__ outv) {
    int wv = threadIdx.x >> 6, l = threadIdx.x & 63;
    int n = blockIdx.x * 4 + wv;
    float acc[10];
    #pragma unroll
    for (int k = 0; k < 10; ++k) acc[k] = 0.f;
    #pragma unroll
    for (int i = 0; i < 5; ++i) {
        int j = l + 64 * i;
        if (j < 288) {
            int c = j / 9;
            float h = fmaf(ss[128 + c], p2[n * 288 + j], ss[160 + c]) + hp1[n * 288 + j];
            #pragma unroll
            for (int k = 0; k < 10; ++k)
                acc[k] = fmaf(h, fw[k * 288 + j], acc[k]);
        }
    }
    #pragma unroll
    for (int k = 0; k < 10; ++k) {
        float s = acc[k];
        #pragma unroll
        for (int o = 32; o > 0; o >>= 1) s += __shfl_down(s, o);
        if (l == 0) outv[n * 10 + k] = s + fb[k];
    }
}

// ---------------------------------------------------------------------------
// Workspace layout (bytes), ~154.2 MB.
//   ss   @1024  768 | w1f @2048 18432(bf16) | w2f @38912 18432(bf16)
//   p0   @76800 102760448 | p1(NHWC) @76800 25690112
//   s1   @25766912 (416 words/img) | hp1 @32582656 | p2 @37301248
//   part1 @60000000 512KB  (dead mid-p0 zone during conv1m->finalize1)
//   s0(NHWC int8) @102837248 25690112
//     part0 (2 MB, conv0->finalize0, before bn0 writes s0) aliases its head
//     part2 (256 KB, conv2m->finalize2, s0 long dead) aliases its head
//   hp0(NHWC) @128527360 25690112
// ---------------------------------------------------------------------------
extern "C" void kernel_launch(void* const* d_in, const int* in_sizes, int n_in,
                              void* d_out, int out_size, void* d_ws, size_t ws_size,
                              hipStream_t stream) {
    (void)in_sizes; (void)n_in; (void)out_size; (void)ws_size;
    const float* x  = (const float*)d_in[0];
    const float* w0 = (const float*)d_in[1];
    const float* g0 = (const float*)d_in[2];
    const float* b0 = (const float*)d_in[3];
    const float* w1 = (const float*)d_in[4];
    const float* g1 = (const float*)d_in[5];
    const float* b1 = (const float*)d_in[6];
    const float* w2 = (const float*)d_in[7];
    const float* g2 = (const float*)d_in[8];
    const float* b2 = (const float*)d_in[9];
    const float* fw = (const float*)d_in[10];
    const float* fb = (const float*)d_in[11];
    float* outv = (float*)d_out;
    char* ws = (char*)d_ws;

    float*     ss    = (float*)(ws + 1024);
    uint16_t*  w1f   = (uint16_t*)(ws + 2048);
    uint16_t*  w2f   = (uint16_t*)(ws + 38912);
    float*     p0    = (float*)(ws + 76800);
    float*     p1    = (float*)(ws + 76800);
    uint32_t*  s1    = (uint32_t*)(ws + 25766912);
    float*     hp1   = (float*)(ws + 32582656);
    float*     p2    = (float*)(ws + 37301248);
    double*    part1 = (double*)(ws + 60000000);
    int8_t*    s0    = (int8_t*)(ws + 102837248);
    double*    part0 = (double*)(ws + 102837248);
    double*    part2 = (double*)(ws + 102837248);
    float*     hp0   = (float*)(ws + 128527360);

    k_signw1<<<36, 256, 0, stream>>>(w1, w1f);
    k_signw1<<<36, 256, 0, stream>>>(w2, w2f);

    k_conv0<<<BATCH, 448, 0, stream>>>(x, w0, p0, part0);
    k_finalize<<<32, 256, 0, stream>>>(part0, 4096, g0, b0, 1.0 / (BATCH * 196.0), ss);
    k_bn0<<<BATCH, 256, 0, stream>>>(p0, ss, s0, hp0);

    k_conv1m<<<BATCH / 4, 256, 0, stream>>>(s0, w1f, p1, part1);
    k_finalize<<<32, 256, 0, stream>>>(part1, 1024, g1, b1, 1.0 / (BATCH * 49.0), ss + 64);
    k_bn1<<<BATCH, 256, 0, stream>>>(p1, hp0, ss, s1, hp1);

    k_conv2m<<<BATCH / 8, 256, 0, stream>>>(s1, w2f, p2, part2);
    k_finalize<<<32, 256, 0, stream>>>(part2, 512, g2, b2, 1.0 / (BATCH * 9.0), ss + 128);

    k_fc<<<BATCH / 4, 256, 0, stream>>>(p2, hp1, ss, fw, fb, outv);
}

// Round 9
// 234.816 us; speedup vs baseline: 1.2017x; 1.2017x over previous
//
#include <hip/hip_runtime.h>
#include <stdint.h>

#define BATCH 4096

typedef float v16f __attribute__((ext_vector_type(16)));
typedef short v8s  __attribute__((ext_vector_type(8)));

__device__ __forceinline__ int sgn8(float v) {
    return (v > 0.f) ? 1 : ((v < 0.f) ? -1 : 0);
}

// ---------------------------------------------------------------------------
// sign(w) -> bf16 MFMA B-fragment layout (used for BOTH w1 and w2):
// o[tp*1024 + kh*512 + q*256 + n*8 + j] = sign(w[n][kh*16+q*8+j][tp]) as bf16
// ---------------------------------------------------------------------------
__global__ void k_signw1(const float* __restrict__ w, uint16_t* __restrict__ o) {
    int i = blockIdx.x * 256 + threadIdx.x;
    if (i >= 9216) return;
    int j = i & 7, n = (i >> 3) & 31, q = (i >> 8) & 1, kh = (i >> 9) & 1, tp = i >> 10;
    int cin = kh * 16 + q * 8 + j;
    float v = w[(n * 32 + cin) * 9 + tp];
    o[i] = (v > 0.f) ? 0x3F80 : ((v < 0.f) ? 0xBF80 : 0);
}

// ---------------------------------------------------------------------------
// conv0: fp32 1->32ch 3x3 pad1 on 28x28 + maxpool2 -> p0 [B][32][14][14],
// fused per-channel double stats.  448 threads.
// THREAD MAP: c = t&31, py = t>>5  (wave = 32 channels x 2 pooled rows) --
// each ds_read_b128 is a 32-lane broadcast x 2 addresses => conflict-free
// despite the 128B row stride (R8's c-major map was ~14-way conflicted).
// xs padded to 32-col stride so float4 reads are aligned; cols 29..31 and
// rows 0/29 are the zero halo.  part0 layout: [c*4096+n] (+32*4096 for sq).
// ---------------------------------------------------------------------------
__global__ __launch_bounds__(448) void k_conv0(const float* __restrict__ x,
                                               const float* __restrict__ w0,
                                               float* __restrict__ p0,
                                               double* __restrict__ part0) {
    __shared__ float xs[960];   // 30 rows x 32 cols
    __shared__ float wl[288];
    __shared__ double rs[32][14], rq[32][14];
    int n = blockIdx.x, t = threadIdx.x;
    for (int i = t; i < 960; i += 448) xs[i] = 0.f;
    for (int i = t; i < 288; i += 448) wl[i] = w0[i];
    __syncthreads();
    for (int i = t; i < 784; i += 448) {
        int y = i / 28, xx = i - y * 28;
        xs[(y + 1) * 32 + xx + 1] = x[n * 784 + i];
    }
    __syncthreads();
    int c = t & 31, py = t >> 5;          // <-- conflict-free mapping
    float wreg[9];
    #pragma unroll
    for (int i = 0; i < 9; ++i) wreg[i] = wl[c * 9 + i];
    const float4* X4 = (const float4*)xs;
    float4 cur0 = X4[(2 * py + 0) * 8];
    float4 cur1 = X4[(2 * py + 1) * 8];
    float4 cur2 = X4[(2 * py + 2) * 8];
    float4 cur3 = X4[(2 * py + 3) * 8];
    double s = 0.0, q = 0.0;
    float* orow = p0 + n * 6272 + c * 196 + py * 14;
    #pragma unroll
    for (int k = 0; k < 7; ++k) {
        float4 n0 = X4[(2 * py + 0) * 8 + k + 1];
        float4 n1 = X4[(2 * py + 1) * 8 + k + 1];
        float4 n2 = X4[(2 * py + 2) * 8 + k + 1];
        float4 n3 = X4[(2 * py + 3) * 8 + k + 1];
        float a[4][6];
        a[0][0] = cur0.x; a[0][1] = cur0.y; a[0][2] = cur0.z; a[0][3] = cur0.w; a[0][4] = n0.x; a[0][5] = n0.y;
        a[1][0] = cur1.x; a[1][1] = cur1.y; a[1][2] = cur1.z; a[1][3] = cur1.w; a[1][4] = n1.x; a[1][5] = n1.y;
        a[2][0] = cur2.x; a[2][1] = cur2.y; a[2][2] = cur2.z; a[2][3] = cur2.w; a[2][4] = n2.x; a[2][5] = n2.y;
        a[3][0] = cur3.x; a[3][1] = cur3.y; a[3][2] = cur3.z; a[3][3] = cur3.w; a[3][4] = n3.x; a[3][5] = n3.y;
        #pragma unroll
        for (int e = 0; e < 2; ++e) {
            int base = 2 * e;
            float s00 = 0.f, s01 = 0.f, s10 = 0.f, s11 = 0.f;
            #pragma unroll
            for (int ky = 0; ky < 3; ++ky)
            #pragma unroll
            for (int kx = 0; kx < 3; ++kx) {
                float w = wreg[ky * 3 + kx];
                s00 = fmaf(a[ky][base + kx], w, s00);
                s01 = fmaf(a[ky][base + kx + 1], w, s01);
                s10 = fmaf(a[ky + 1][base + kx], w, s10);
                s11 = fmaf(a[ky + 1][base + kx + 1], w, s11);
            }
            float m = fmaxf(fmaxf(s00, s01), fmaxf(s10, s11));
            orow[2 * k + e] = m;
            double v = (double)m;
            s += v; q += v * v;
        }
        cur0 = n0; cur1 = n1; cur2 = n2; cur3 = n3;
    }
    rs[c][py] = s; rq[c][py] = q;
    __syncthreads();
    if (t < 32) {
        double S = 0.0, Q = 0.0;
        #pragma unroll
        for (int i = 0; i < 14; ++i) { S += rs[t][i]; Q += rq[t][i]; }
        part0[(size_t)t * 4096 + n] = S;
        part0[(size_t)32 * 4096 + (size_t)t * 4096 + n] = Q;
    }
}

// ---------------------------------------------------------------------------
// finalize: grid(32) x 256 threads. Block = channel. Fixed-order reduction
// of G partials, layout part[c*G+i] (sums) / part[32G + c*G+i] (sumsq) --
// contiguous per channel => coalesced. double math; deterministic.
// ---------------------------------------------------------------------------
__global__ __launch_bounds__(256) void k_finalize(const double* __restrict__ part, int G,
                                                  const float* __restrict__ g,
                                                  const float* __restrict__ b,
                                                  double inv_count, float* __restrict__ ss) {
    int c = blockIdx.x, t = threadIdx.x;
    double s = 0.0, q = 0.0;
    for (int i = t; i < G; i += 256) {
        s += part[(size_t)c * G + i];
        q += part[(size_t)32 * G + (size_t)c * G + i];
    }
    #pragma unroll
    for (int o = 32; o > 0; o >>= 1) { s += __shfl_down(s, o); q += __shfl_down(q, o); }
    __shared__ double rs[4], rq[4];
    int w = t >> 6, l = t & 63;
    if (l == 0) { rs[w] = s; rq[w] = q; }
    __syncthreads();
    if (t == 0) {
        s = rs[0] + rs[1] + rs[2] + rs[3];
        q = rq[0] + rq[1] + rq[2] + rq[3];
        double mean = s * inv_count;
        double var = q * inv_count - mean * mean;
        double sc = (double)g[c] / sqrt(var + 1e-5);
        ss[c] = (float)sc;
        ss[32 + c] = (float)((double)b[c] - mean * sc);
    }
}

// ---------------------------------------------------------------------------
// bn0: block per image. p0 NCHW staged in LDS; writes s0 NHWC int8
// [n][196][32] and hp0 NHWC fp32 [n][49][32].
// ---------------------------------------------------------------------------
__global__ __launch_bounds__(256) void k_bn0(const float* __restrict__ p0,
                                             const float* __restrict__ ss,
                                             int8_t* __restrict__ s0,
                                             float* __restrict__ hp0) {
    __shared__ float P[6272];
    int n = blockIdx.x, t = threadIdx.x;
    const float* src = p0 + n * 6272;
    for (int i = t; i < 6272; i += 256) P[i] = src[i];
    __syncthreads();
    if (t < 196) {
        int p = t;
        uint32_t pk[8];
        #pragma unroll
        for (int cg = 0; cg < 8; ++cg) {
            uint32_t u = 0;
            #pragma unroll
            for (int k = 0; k < 4; ++k) {
                int c = cg * 4 + k;
                float v = fmaf(ss[c], P[c * 196 + p], ss[32 + c]);
                u |= ((uint32_t)(uint8_t)(int8_t)sgn8(v)) << (8 * k);
            }
            pk[cg] = u;
        }
        uint4* dst = (uint4*)(s0 + (size_t)n * 6272 + p * 32);
        uint4 v0; v0.x = pk[0]; v0.y = pk[1]; v0.z = pk[2]; v0.w = pk[3];
        uint4 v1; v1.x = pk[4]; v1.y = pk[5]; v1.z = pk[6]; v1.w = pk[7];
        dst[0] = v0; dst[1] = v1;

        int pw = t >> 2, oct = t & 3;           // 49 pw x 4 octs = 196
        int py = pw / 7, px = pw - py * 7;
        float out[8];
        #pragma unroll
        for (int k = 0; k < 8; ++k) {
            int c = oct * 8 + k;
            float sc = ss[c], sh = ss[32 + c];
            const float* B = &P[c * 196];
            float a0 = fmaf(sc, B[(2 * py) * 14 + 2 * px], sh);
            float a1 = fmaf(sc, B[(2 * py) * 14 + 2 * px + 1], sh);
            float a2 = fmaf(sc, B[(2 * py + 1) * 14 + 2 * px], sh);
            float a3 = fmaf(sc, B[(2 * py + 1) * 14 + 2 * px + 1], sh);
            out[k] = fmaxf(fmaxf(a0, a1), fmaxf(a2, a3));
        }
        float4* hd = (float4*)(hp0 + ((size_t)n * 49 + pw) * 32 + oct * 8);
        float4 h0; h0.x = out[0]; h0.y = out[1]; h0.z = out[2]; h0.w = out[3];
        float4 h1; h1.x = out[4]; h1.y = out[5]; h1.z = out[6]; h1.w = out[7];
        hd[0] = h0; hd[1] = h1;
    }
}

// ---------------------------------------------------------------------------
// conv1 bf16 MFMA implicit GEMM, 4 images/block, fused stats (G=1024,
// part layout [c*1024+b] / +32*1024 for sq).
// ---------------------------------------------------------------------------
__global__ __launch_bounds__(256) void k_conv1m(const int8_t* __restrict__ s0,
                                                const uint16_t* __restrict__ w1f,
                                                float* __restrict__ p1,
                                                double* __restrict__ part1) {
    __shared__ uint32_t lds[16384];   // 64 KB: 4 images x 256 pixels x 16 dwords
    int t = threadIdx.x;
    int n0 = blockIdx.x * 4;
    if (t < 240) {
        int img = t / 60, e = t % 60;
        int yh, xh;
        if (e < 16)      { yh = 0;      xh = e; }
        else if (e < 32) { yh = 15;     xh = e - 16; }
        else if (e < 46) { yh = e - 31; xh = 0; }
        else             { yh = e - 45; xh = 15; }
        uint32_t* d = &lds[img * 4096 + (yh * 16 + xh) * 16];
        uint4 z; z.x = z.y = z.z = z.w = 0u;
        ((uint4*)d)[0] = z; ((uint4*)d)[1] = z; ((uint4*)d)[2] = z; ((uint4*)d)[3] = z;
    }
    int lane = t & 63, wv = t >> 6;
    int q = lane >> 5, ncol = lane & 31;
    v8s wfr[18];
    #pragma unroll
    for (int f = 0; f < 18; ++f)
        wfr[f] = *(const v8s*)(w1f + (f * 2 + q) * 256 + ncol * 8);
    for (int i = t; i < 6272; i += 256) {
        int img = i / 1568, r = i - img * 1568;
        int pimg = r >> 3, dp = r & 7;
        int iy = pimg / 14, ix = pimg - iy * 14;
        int p = (iy + 1) * 16 + ix + 1;
        uint32_t u = ((const uint32_t*)s0)[(size_t)(n0 + img) * 1568 + r];
        uint32_t b0 = u & 0xFF, b1 = (u >> 8) & 0xFF, b2 = (u >> 16) & 0xFF, b3 = u >> 24;
        uint32_t h0 = b0 ? (0x3F80u | ((b0 & 0x80u) << 8)) : 0u;
        uint32_t h1 = b1 ? (0x3F80u | ((b1 & 0x80u) << 8)) : 0u;
        uint32_t h2 = b2 ? (0x3F80u | ((b2 & 0x80u) << 8)) : 0u;
        uint32_t h3 = b3 ? (0x3F80u | ((b3 & 0x80u) << 8)) : 0u;
        int g = dp >> 1;
        int gs = g ^ (p & 3);
        int idx = img * 4096 + p * 16 + (gs << 2) + ((dp & 1) << 1);
        lds[idx] = h0 | (h1 << 16);
        lds[idx + 1] = h2 | (h3 << 16);
    }
    __syncthreads();
    int n = n0 + wv;
    int ibase = wv * 4096;
    int m = lane & 31;
    int quad = m & 3, pwl = m >> 2;
    int dy = quad >> 1, dx = quad & 1;
    double sAcc = 0.0, qAcc = 0.0;
    for (int tile = 0; tile < 7; ++tile) {
        int pw = tile * 8 + pwl;
        int pwc = min(pw, 48);
        int py = pwc / 7, px = pwc - py * 7;
        int pbase = (2 * py + dy) * 16 + 2 * px + dx;
        v16f acc;
        #pragma unroll
        for (int i = 0; i < 16; ++i) acc[i] = 0.f;
        #pragma unroll
        for (int tp = 0; tp < 9; ++tp) {
            int p = pbase + (tp / 3) * 16 + (tp % 3);
            int psw = p & 3;
            #pragma unroll
            for (int kh = 0; kh < 2; ++kh) {
                int g = kh * 2 + q;
                int idx = ibase + p * 16 + ((g ^ psw) << 2);
                v8s a = *(const v8s*)&lds[idx];
                acc = __builtin_amdgcn_mfma_f32_32x32x16_bf16(a, wfr[tp * 2 + kh], acc, 0, 0, 0);
            }
        }
        #pragma unroll
        for (int g4 = 0; g4 < 4; ++g4) {
            float mx = fmaxf(fmaxf(acc[4 * g4], acc[4 * g4 + 1]),
                             fmaxf(acc[4 * g4 + 2], acc[4 * g4 + 3]));
            int pwo = tile * 8 + 2 * g4 + q;
            if (pwo < 49) {
                p1[((size_t)n * 49 + pwo) * 32 + ncol] = mx;
                double v = (double)mx;
                sAcc += v; qAcc += v * v;
            }
        }
    }
    __syncthreads();
    double* red = (double*)lds;   // act LDS dead; 512 doubles used
    red[(wv * 2 + q) * 32 + ncol] = sAcc;
    red[256 + (wv * 2 + q) * 32 + ncol] = qAcc;
    __syncthreads();
    if (t < 32) {
        double S = 0.0, Q = 0.0;
        #pragma unroll
        for (int i = 0; i < 8; ++i) { S += red[i * 32 + t]; Q += red[256 + i * 32 + t]; }
        part1[(size_t)t * 1024 + blockIdx.x] = S;
        part1[(size_t)32 * 1024 + (size_t)t * 1024 + blockIdx.x] = Q;
    }
}

// ---------------------------------------------------------------------------
// bn1: block per image. h = bn1(p1) + hp0 (both NHWC) in LDS; emits
// s1 NCHW-packed (for conv2m) and hp1 NCHW [n][c][9] (for FC).
// s1 image stride = 416 WORDS (32 ch x 13 words).
// ---------------------------------------------------------------------------
__global__ __launch_bounds__(256) void k_bn1(const float* __restrict__ p1,
                                             const float* __restrict__ hp0,
                                             const float* __restrict__ ss,
                                             uint32_t* __restrict__ s1,
                                             float* __restrict__ hp1) {
    __shared__ float H[1568];
    int n = blockIdx.x, t = threadIdx.x;
    const float* P = p1 + (size_t)n * 1568;
    const float* Hp = hp0 + (size_t)n * 1568;
    for (int i = t; i < 1568; i += 256) {
        int c = i & 31;
        H[i] = fmaf(ss[64 + c], P[i], ss[96 + c]) + Hp[i];
    }
    __syncthreads();
    if (t < 32) {
        int c = t;
        uint32_t* sp = s1 + (size_t)n * 416 + c * 13;
        for (int j = 0; j < 13; ++j) {
            uint32_t u = 0;
            #pragma unroll
            for (int k = 0; k < 4; ++k) {
                int f = 4 * j + k;
                int sv = (f < 49) ? sgn8(H[f * 32 + c]) : 0;
                u |= ((uint32_t)(uint8_t)(int8_t)sv) << (8 * k);
            }
            sp[j] = u;
        }
    }
    for (int jj = t; jj < 288; jj += 256) {
        int c = jj / 9, pix = jj - c * 9;
        int r = pix / 3, qq = pix - r * 3;
        float a0 = H[((2 * r) * 7 + 2 * qq) * 32 + c];
        float a1 = H[((2 * r) * 7 + 2 * qq + 1) * 32 + c];
        float a2 = H[((2 * r + 1) * 7 + 2 * qq) * 32 + c];
        float a3 = H[((2 * r + 1) * 7 + 2 * qq + 1) * 32 + c];
        hp1[n * 288 + c * 9 + pix] = fmaxf(fmaxf(a0, a1), fmaxf(a2, a3));
    }
}

// ---------------------------------------------------------------------------
// conv2 via bf16 MFMA implicit GEMM + fused stats. 8 images/block.
// part2 layout [c*512+b] / +32*512 for sq. p2 NCHW [n][32][9].
// ---------------------------------------------------------------------------
__global__ __launch_bounds__(256) void k_conv2m(const uint32_t* __restrict__ s1,
                                                const uint16_t* __restrict__ w2f,
                                                float* __restrict__ p2,
                                                double* __restrict__ part2) {
    __shared__ uint32_t lds[8192];   // 32 KB
    int t = threadIdx.x;
    int n0 = blockIdx.x * 8;
    for (int i = t; i < 120; i += 256) {
        int img = i / 15, e = i - img * 15;
        int p = (e < 8) ? e : (e - 7) * 8;
        uint32_t* d = &lds[img * 1024 + p * 16];
        uint4 z; z.x = z.y = z.z = z.w = 0u;
        ((uint4*)d)[0] = z; ((uint4*)d)[1] = z; ((uint4*)d)[2] = z; ((uint4*)d)[3] = z;
    }
    int lane = t & 63, wv = t >> 6;
    int q = lane >> 5, ncol = lane & 31;
    v8s wfr[18];
    #pragma unroll
    for (int f = 0; f < 18; ++f)
        wfr[f] = *(const v8s*)(w2f + (f * 2 + q) * 256 + ncol * 8);
    for (int i = t; i < 1664; i += 256) {
        int img = i / 208, r = i - img * 208;
        int c2 = r / 13, j = r - c2 * 13;
        const uint32_t* sb = s1 + (size_t)(n0 + img) * 416;
        uint32_t wa = sb[(2 * c2) * 13 + j];
        uint32_t wb = sb[(2 * c2 + 1) * 13 + j];
        int g = c2 >> 2, sub = c2 & 3;
        #pragma unroll
        for (int k = 0; k < 4; ++k) {
            int f = 4 * j + k;
            if (f < 49) {
                int y = f / 7, x = f - y * 7;
                int p = (y + 1) * 8 + (x + 1);
                uint32_t ba = (wa >> (8 * k)) & 0xFF;
                uint32_t bb = (wb >> (8 * k)) & 0xFF;
                uint32_t ha = ba ? (0x3F80u | ((ba & 0x80u) << 8)) : 0u;
                uint32_t hb = bb ? (0x3F80u | ((bb & 0x80u) << 8)) : 0u;
                lds[img * 1024 + p * 16 + ((g ^ (p & 3)) << 2) + sub] = ha | (hb << 16);
            }
        }
    }
    __syncthreads();
    int m = lane & 31;
    int quad = m & 3, pwl = m >> 2;
    int dy = quad >> 1, dx = quad & 1;
    double sAcc = 0.0, qAcc = 0.0;
    for (int tile = wv; tile < 9; tile += 4) {
        int pwg = tile * 8 + pwl;                    // 0..71
        int img = pwg / 9, pwi = pwg - img * 9;
        int py = pwi / 3, px = pwi - py * 3;
        int pbase = (2 * py + dy) * 8 + 2 * px + dx;
        v16f acc;
        #pragma unroll
        for (int i = 0; i < 16; ++i) acc[i] = 0.f;
        #pragma unroll
        for (int tp = 0; tp < 9; ++tp) {
            int p = pbase + (tp / 3) * 8 + (tp % 3);
            int psw = p & 3;
            #pragma unroll
            for (int kh = 0; kh < 2; ++kh) {
                int g = kh * 2 + q;
                int idx = img * 1024 + p * 16 + ((g ^ psw) << 2);
                v8s a = *(const v8s*)&lds[idx];
                acc = __builtin_amdgcn_mfma_f32_32x32x16_bf16(a, wfr[tp * 2 + kh], acc, 0, 0, 0);
            }
        }
        #pragma unroll
        for (int g4 = 0; g4 < 4; ++g4) {
            float mx = fmaxf(fmaxf(acc[4 * g4], acc[4 * g4 + 1]),
                             fmaxf(acc[4 * g4 + 2], acc[4 * g4 + 3]));
            int pwo = tile * 8 + 2 * g4 + q;          // 0..71
            int oimg = pwo / 9, opwi = pwo - oimg * 9;
            p2[(size_t)(n0 + oimg) * 288 + ncol * 9 + opwi] = mx;
            double v = (double)mx;
            sAcc += v; qAcc += v * v;
        }
    }
    __syncthreads();
    double* red = (double*)lds;   // act LDS dead; 512 doubles
    red[(wv * 2 + q) * 32 + ncol] = sAcc;
    red[256 + (wv * 2 + q) * 32 + ncol] = qAcc;
    __syncthreads();
    if (t < 32) {
        double S = 0.0, Q = 0.0;
        #pragma unroll
        for (int i = 0; i < 8; ++i) { S += red[i * 32 + t]; Q += red[256 + i * 32 + t]; }
        part2[(size_t)t * 512 + blockIdx.x] = S;
        part2[(size_t)32 * 512 + (size_t)t * 512 + blockIdx.x] = Q;
    }
}

// ---------------------------------------------------------------------------
// FC: out[n,k] = sum_j (bn2(p2)+hp1)[n,j] * fw[k,j] + fb[k].  Wave per image.
// ---------------------------------------------------------------------------
__global__ __launch_bounds__(256) void k_fc(const float* __restrict__ p2,
                                            const float* __restrict__ hp1,
                                            const float* __restrict__ ss,
                                            const float* __restrict__ fw,
                                            const float* __restrict__ fb,
                                            float* __restrict__ outv) {
    int wv = threadIdx.x >> 6, l = threadIdx.x & 63;
    int n = blockIdx.x * 4 + wv;
    float acc[10];
    #pragma unroll
    for (int k = 0; k < 10; ++k) acc[k] = 0.f;
    #pragma unroll
    for (int i = 0; i < 5; ++i) {
        int j = l + 64 * i;
        if (j < 288) {
            int c = j / 9;
            float h = fmaf(ss[128 + c], p2[n * 288 + j], ss[160 + c]) + hp1[n * 288 + j];
            #pragma unroll
            for (int k = 0; k < 10; ++k)
                acc[k] = fmaf(h, fw[k * 288 + j], acc[k]);
        }
    }
    #pragma unroll
    for (int k = 0; k < 10; ++k) {
        float s = acc[k];
        #pragma unroll
        for (int o = 32; o > 0; o >>= 1) s += __shfl_down(s, o);
        if (l == 0) outv[n * 10 + k] = s + fb[k];
    }
}

// ---------------------------------------------------------------------------
// Workspace layout (bytes), ~154.2 MB.
//   ss   @1024  768 | w1f @2048 18432(bf16) | w2f @38912 18432(bf16)
//   p0   @76800 102760448 | p1(NHWC) @76800 25690112
//   s1   @25766912 (416 words/img) | hp1 @32582656 | p2 @37301248
//   part1 @60000000 512KB  (dead mid-p0 zone during conv1m->finalize1)
//   s0(NHWC int8) @102837248 25690112
//     part0 (2 MB, conv0->finalize0, before bn0 writes s0) aliases its head
//     part2 (256 KB, conv2m->finalize2, s0 long dead) aliases its head
//   hp0(NHWC) @128527360 25690112
// ---------------------------------------------------------------------------
extern "C" void kernel_launch(void* const* d_in, const int* in_sizes, int n_in,
                              void* d_out, int out_size, void* d_ws, size_t ws_size,
                              hipStream_t stream) {
    (void)in_sizes; (void)n_in; (void)out_size; (void)ws_size;
    const float* x  = (const float*)d_in[0];
    const float* w0 = (const float*)d_in[1];
    const float* g0 = (const float*)d_in[2];
    const float* b0 = (const float*)d_in[3];
    const float* w1 = (const float*)d_in[4];
    const float* g1 = (const float*)d_in[5];
    const float* b1 = (const float*)d_in[6];
    const float* w2 = (const float*)d_in[7];
    const float* g2 = (const float*)d_in[8];
    const float* b2 = (const float*)d_in[9];
    const float* fw = (const float*)d_in[10];
    const float* fb = (const float*)d_in[11];
    float* outv = (float*)d_out;
    char* ws = (char*)d_ws;

    float*     ss    = (float*)(ws + 1024);
    uint16_t*  w1f   = (uint16_t*)(ws + 2048);
    uint16_t*  w2f   = (uint16_t*)(ws + 38912);
    float*     p0    = (float*)(ws + 76800);
    float*     p1    = (float*)(ws + 76800);
    uint32_t*  s1    = (uint32_t*)(ws + 25766912);
    float*     hp1   = (float*)(ws + 32582656);
    float*     p2    = (float*)(ws + 37301248);
    double*    part1 = (double*)(ws + 60000000);
    int8_t*    s0    = (int8_t*)(ws + 102837248);
    double*    part0 = (double*)(ws + 102837248);
    double*    part2 = (double*)(ws + 102837248);
    float*     hp0   = (float*)(ws + 128527360);

    k_signw1<<<36, 256, 0, stream>>>(w1, w1f);
    k_signw1<<<36, 256, 0, stream>>>(w2, w2f);

    k_conv0<<<BATCH, 448, 0, stream>>>(x, w0, p0, part0);
    k_finalize<<<32, 256, 0, stream>>>(part0, 4096, g0, b0, 1.0 / (BATCH * 196.0), ss);
    k_bn0<<<BATCH, 256, 0, stream>>>(p0, ss, s0, hp0);

    k_conv1m<<<BATCH / 4, 256, 0, stream>>>(s0, w1f, p1, part1);
    k_finalize<<<32, 256, 0, stream>>>(part1, 1024, g1, b1, 1.0 / (BATCH * 49.0), ss + 64);
    k_bn1<<<BATCH, 256, 0, stream>>>(p1, hp0, ss, s1, hp1);

    k_conv2m<<<BATCH / 8, 256, 0, stream>>>(s1, w2f, p2, part2);
    k_finalize<<<32, 256, 0, stream>>>(part2, 512, g2, b2, 1.0 / (BATCH * 9.0), ss + 128);

    k_fc<<<BATCH / 4, 256, 0, stream>>>(p2, hp1, ss, fw, fb, outv);
}

// Round 10
// 223.039 us; speedup vs baseline: 1.2652x; 1.0528x over previous
//
#include <hip/hip_runtime.h>
#include <stdint.h>

#define BATCH 4096

typedef float v16f __attribute__((ext_vector_type(16)));
typedef short v8s  __attribute__((ext_vector_type(8)));

__device__ __forceinline__ int sgn8(float v) {
    return (v > 0.f) ? 1 : ((v < 0.f) ? -1 : 0);
}

// ---------------------------------------------------------------------------
// sign(w) -> bf16 MFMA B-fragment layout (used for BOTH w1 and w2):
// o[tp*1024 + kh*512 + q*256 + n*8 + j] = sign(w[n][kh*16+q*8+j][tp]) as bf16
// ---------------------------------------------------------------------------
__global__ void k_signw1(const float* __restrict__ w, uint16_t* __restrict__ o) {
    int i = blockIdx.x * 256 + threadIdx.x;
    if (i >= 9216) return;
    int j = i & 7, n = (i >> 3) & 31, q = (i >> 8) & 1, kh = (i >> 9) & 1, tp = i >> 10;
    int cin = kh * 16 + q * 8 + j;
    float v = w[(n * 32 + cin) * 9 + tp];
    o[i] = (v > 0.f) ? 0x3F80 : ((v < 0.f) ? 0xBF80 : 0);
}

// ---------------------------------------------------------------------------
// conv0: fp32 1->32ch 3x3 pad1 on 28x28 + maxpool2 -> p0 NHWC [B][196][32],
// fused per-channel double stats.  448 threads, c = t&31, py = t>>5
// (conflict-free LDS reads: 32-lane broadcast x 2 addrs per ds_read_b128).
// NHWC store => lanes 0..31 write 128B contiguous (coalesced), fixing R9's
// 64-line scattered NCHW stores.  part0 layout [c*4096+n] (+32*4096 sq).
// ---------------------------------------------------------------------------
__global__ __launch_bounds__(448) void k_conv0(const float* __restrict__ x,
                                               const float* __restrict__ w0,
                                               float* __restrict__ p0,
                                               double* __restrict__ part0) {
    __shared__ float xs[960];   // 30 rows x 32 cols (zero halo)
    __shared__ float wl[288];
    __shared__ double rs[32][14], rq[32][14];
    int n = blockIdx.x, t = threadIdx.x;
    for (int i = t; i < 960; i += 448) xs[i] = 0.f;
    for (int i = t; i < 288; i += 448) wl[i] = w0[i];
    __syncthreads();
    for (int i = t; i < 784; i += 448) {
        int y = i / 28, xx = i - y * 28;
        xs[(y + 1) * 32 + xx + 1] = x[n * 784 + i];
    }
    __syncthreads();
    int c = t & 31, py = t >> 5;
    float wreg[9];
    #pragma unroll
    for (int i = 0; i < 9; ++i) wreg[i] = wl[c * 9 + i];
    const float4* X4 = (const float4*)xs;
    float4 cur0 = X4[(2 * py + 0) * 8];
    float4 cur1 = X4[(2 * py + 1) * 8];
    float4 cur2 = X4[(2 * py + 2) * 8];
    float4 cur3 = X4[(2 * py + 3) * 8];
    double s = 0.0, q = 0.0;
    float* obase = p0 + ((size_t)n * 196 + py * 14) * 32 + c;   // NHWC
    #pragma unroll
    for (int k = 0; k < 7; ++k) {
        float4 n0 = X4[(2 * py + 0) * 8 + k + 1];
        float4 n1 = X4[(2 * py + 1) * 8 + k + 1];
        float4 n2 = X4[(2 * py + 2) * 8 + k + 1];
        float4 n3 = X4[(2 * py + 3) * 8 + k + 1];
        float a[4][6];
        a[0][0] = cur0.x; a[0][1] = cur0.y; a[0][2] = cur0.z; a[0][3] = cur0.w; a[0][4] = n0.x; a[0][5] = n0.y;
        a[1][0] = cur1.x; a[1][1] = cur1.y; a[1][2] = cur1.z; a[1][3] = cur1.w; a[1][4] = n1.x; a[1][5] = n1.y;
        a[2][0] = cur2.x; a[2][1] = cur2.y; a[2][2] = cur2.z; a[2][3] = cur2.w; a[2][4] = n2.x; a[2][5] = n2.y;
        a[3][0] = cur3.x; a[3][1] = cur3.y; a[3][2] = cur3.z; a[3][3] = cur3.w; a[3][4] = n3.x; a[3][5] = n3.y;
        #pragma unroll
        for (int e = 0; e < 2; ++e) {
            int base = 2 * e;
            float s00 = 0.f, s01 = 0.f, s10 = 0.f, s11 = 0.f;
            #pragma unroll
            for (int ky = 0; ky < 3; ++ky)
            #pragma unroll
            for (int kx = 0; kx < 3; ++kx) {
                float w = wreg[ky * 3 + kx];
                s00 = fmaf(a[ky][base + kx], w, s00);
                s01 = fmaf(a[ky][base + kx + 1], w, s01);
                s10 = fmaf(a[ky + 1][base + kx], w, s10);
                s11 = fmaf(a[ky + 1][base + kx + 1], w, s11);
            }
            float m = fmaxf(fmaxf(s00, s01), fmaxf(s10, s11));
            obase[(2 * k + e) * 32] = m;
            double v = (double)m;
            s += v; q += v * v;
        }
        cur0 = n0; cur1 = n1; cur2 = n2; cur3 = n3;
    }
    rs[c][py] = s; rq[c][py] = q;
    __syncthreads();
    if (t < 32) {
        double S = 0.0, Q = 0.0;
        #pragma unroll
        for (int i = 0; i < 14; ++i) { S += rs[t][i]; Q += rq[t][i]; }
        part0[(size_t)t * 4096 + n] = S;
        part0[(size_t)32 * 4096 + (size_t)t * 4096 + n] = Q;
    }
}

// ---------------------------------------------------------------------------
// finalize: grid(32) x 256 threads. Block = channel. Fixed-order reduction
// of G partials, layout part[c*G+i] / part[32G+c*G+i]; coalesced; double.
// ---------------------------------------------------------------------------
__global__ __launch_bounds__(256) void k_finalize(const double* __restrict__ part, int G,
                                                  const float* __restrict__ g,
                                                  const float* __restrict__ b,
                                                  double inv_count, float* __restrict__ ss) {
    int c = blockIdx.x, t = threadIdx.x;
    double s = 0.0, q = 0.0;
    for (int i = t; i < G; i += 256) {
        s += part[(size_t)c * G + i];
        q += part[(size_t)32 * G + (size_t)c * G + i];
    }
    #pragma unroll
    for (int o = 32; o > 0; o >>= 1) { s += __shfl_down(s, o); q += __shfl_down(q, o); }
    __shared__ double rs[4], rq[4];
    int w = t >> 6, l = t & 63;
    if (l == 0) { rs[w] = s; rq[w] = q; }
    __syncthreads();
    if (t == 0) {
        s = rs[0] + rs[1] + rs[2] + rs[3];
        q = rq[0] + rq[1] + rq[2] + rq[3];
        double mean = s * inv_count;
        double var = q * inv_count - mean * mean;
        double sc = (double)g[c] / sqrt(var + 1e-5);
        ss[c] = (float)sc;
        ss[32 + c] = (float)((double)b[c] - mean * sc);
    }
}

// ---------------------------------------------------------------------------
// bn0: block per image, p0 NHWC in -> s0 NHWC int8 + hp0 NHWC fp32.
// Pass 1 (coalesced float4): h = BN(p0), write s0 word, stash h in LDS
// (stride 33 = +1 pad, conflict-free).  Pass 2: 2x2 maxpool from LDS.
// No transpose anywhere.
// ---------------------------------------------------------------------------
__global__ __launch_bounds__(256) void k_bn0(const float* __restrict__ p0,
                                             const float* __restrict__ ss,
                                             int8_t* __restrict__ s0,
                                             float* __restrict__ hp0) {
    __shared__ float P[6468];    // 196 x 33
    __shared__ float SS[64];
    int n = blockIdx.x, t = threadIdx.x;
    if (t < 64) SS[t] = ss[t];
    __syncthreads();
    const float4* src4 = (const float4*)(p0 + (size_t)n * 6272);
    uint32_t* s0w = (uint32_t*)(s0 + (size_t)n * 6272);
    for (int i = t; i < 1568; i += 256) {
        int pix = i >> 3, cg = i & 7;
        float4 v = src4[i];
        int c0 = cg * 4;
        float h0 = fmaf(SS[c0],     v.x, SS[32 + c0]);
        float h1 = fmaf(SS[c0 + 1], v.y, SS[33 + c0]);
        float h2 = fmaf(SS[c0 + 2], v.z, SS[34 + c0]);
        float h3 = fmaf(SS[c0 + 3], v.w, SS[35 + c0]);
        uint32_t u = (uint32_t)(uint8_t)(int8_t)sgn8(h0)
                   | ((uint32_t)(uint8_t)(int8_t)sgn8(h1)) << 8
                   | ((uint32_t)(uint8_t)(int8_t)sgn8(h2)) << 16
                   | ((uint32_t)(uint8_t)(int8_t)sgn8(h3)) << 24;
        s0w[i] = u;
        float* Pp = &P[pix * 33 + c0];
        Pp[0] = h0; Pp[1] = h1; Pp[2] = h2; Pp[3] = h3;
    }
    __syncthreads();
    if (t < 196) {
        int pw = t >> 2, oct = t & 3;           // 49 pw x 4 octs
        int py = pw / 7, px = pw - py * 7;
        int b00 = ((2 * py) * 14 + 2 * px) * 33;
        int b01 = b00 + 33;
        int b10 = b00 + 14 * 33;
        int b11 = b10 + 33;
        float out[8];
        #pragma unroll
        for (int k = 0; k < 8; ++k) {
            int c = oct * 8 + k;
            out[k] = fmaxf(fmaxf(P[b00 + c], P[b01 + c]),
                           fmaxf(P[b10 + c], P[b11 + c]));
        }
        float4* hd = (float4*)(hp0 + ((size_t)n * 49 + pw) * 32 + oct * 8);
        float4 h0; h0.x = out[0]; h0.y = out[1]; h0.z = out[2]; h0.w = out[3];
        float4 h1; h1.x = out[4]; h1.y = out[5]; h1.z = out[6]; h1.w = out[7];
        hd[0] = h0; hd[1] = h1;
    }
}

// ---------------------------------------------------------------------------
// conv1 bf16 MFMA implicit GEMM, 4 images/block, fused stats (G=1024,
// part layout [c*1024+b] / +32*1024 for sq).
// ---------------------------------------------------------------------------
__global__ __launch_bounds__(256) void k_conv1m(const int8_t* __restrict__ s0,
                                                const uint16_t* __restrict__ w1f,
                                                float* __restrict__ p1,
                                                double* __restrict__ part1) {
    __shared__ uint32_t lds[16384];   // 64 KB: 4 images x 256 pixels x 16 dwords
    int t = threadIdx.x;
    int n0 = blockIdx.x * 4;
    if (t < 240) {
        int img = t / 60, e = t % 60;
        int yh, xh;
        if (e < 16)      { yh = 0;      xh = e; }
        else if (e < 32) { yh = 15;     xh = e - 16; }
        else if (e < 46) { yh = e - 31; xh = 0; }
        else             { yh = e - 45; xh = 15; }
        uint32_t* d = &lds[img * 4096 + (yh * 16 + xh) * 16];
        uint4 z; z.x = z.y = z.z = z.w = 0u;
        ((uint4*)d)[0] = z; ((uint4*)d)[1] = z; ((uint4*)d)[2] = z; ((uint4*)d)[3] = z;
    }
    int lane = t & 63, wv = t >> 6;
    int q = lane >> 5, ncol = lane & 31;
    v8s wfr[18];
    #pragma unroll
    for (int f = 0; f < 18; ++f)
        wfr[f] = *(const v8s*)(w1f + (f * 2 + q) * 256 + ncol * 8);
    for (int i = t; i < 6272; i += 256) {
        int img = i / 1568, r = i - img * 1568;
        int pimg = r >> 3, dp = r & 7;
        int iy = pimg / 14, ix = pimg - iy * 14;
        int p = (iy + 1) * 16 + ix + 1;
        uint32_t u = ((const uint32_t*)s0)[(size_t)(n0 + img) * 1568 + r];
        uint32_t b0 = u & 0xFF, b1 = (u >> 8) & 0xFF, b2 = (u >> 16) & 0xFF, b3 = u >> 24;
        uint32_t h0 = b0 ? (0x3F80u | ((b0 & 0x80u) << 8)) : 0u;
        uint32_t h1 = b1 ? (0x3F80u | ((b1 & 0x80u) << 8)) : 0u;
        uint32_t h2 = b2 ? (0x3F80u | ((b2 & 0x80u) << 8)) : 0u;
        uint32_t h3 = b3 ? (0x3F80u | ((b3 & 0x80u) << 8)) : 0u;
        int g = dp >> 1;
        int gs = g ^ (p & 3);
        int idx = img * 4096 + p * 16 + (gs << 2) + ((dp & 1) << 1);
        lds[idx] = h0 | (h1 << 16);
        lds[idx + 1] = h2 | (h3 << 16);
    }
    __syncthreads();
    int n = n0 + wv;
    int ibase = wv * 4096;
    int m = lane & 31;
    int quad = m & 3, pwl = m >> 2;
    int dy = quad >> 1, dx = quad & 1;
    double sAcc = 0.0, qAcc = 0.0;
    for (int tile = 0; tile < 7; ++tile) {
        int pw = tile * 8 + pwl;
        int pwc = min(pw, 48);
        int py = pwc / 7, px = pwc - py * 7;
        int pbase = (2 * py + dy) * 16 + 2 * px + dx;
        v16f acc;
        #pragma unroll
        for (int i = 0; i < 16; ++i) acc[i] = 0.f;
        #pragma unroll
        for (int tp = 0; tp < 9; ++tp) {
            int p = pbase + (tp / 3) * 16 + (tp % 3);
            int psw = p & 3;
            #pragma unroll
            for (int kh = 0; kh < 2; ++kh) {
                int g = kh * 2 + q;
                int idx = ibase + p * 16 + ((g ^ psw) << 2);
                v8s a = *(const v8s*)&lds[idx];
                acc = __builtin_amdgcn_mfma_f32_32x32x16_bf16(a, wfr[tp * 2 + kh], acc, 0, 0, 0);
            }
        }
        #pragma unroll
        for (int g4 = 0; g4 < 4; ++g4) {
            float mx = fmaxf(fmaxf(acc[4 * g4], acc[4 * g4 + 1]),
                             fmaxf(acc[4 * g4 + 2], acc[4 * g4 + 3]));
            int pwo = tile * 8 + 2 * g4 + q;
            if (pwo < 49) {
                p1[((size_t)n * 49 + pwo) * 32 + ncol] = mx;
                double v = (double)mx;
                sAcc += v; qAcc += v * v;
            }
        }
    }
    __syncthreads();
    double* red = (double*)lds;   // act LDS dead; 512 doubles used
    red[(wv * 2 + q) * 32 + ncol] = sAcc;
    red[256 + (wv * 2 + q) * 32 + ncol] = qAcc;
    __syncthreads();
    if (t < 32) {
        double S = 0.0, Q = 0.0;
        #pragma unroll
        for (int i = 0; i < 8; ++i) { S += red[i * 32 + t]; Q += red[256 + i * 32 + t]; }
        part1[(size_t)t * 1024 + blockIdx.x] = S;
        part1[(size_t)32 * 1024 + (size_t)t * 1024 + blockIdx.x] = Q;
    }
}

// ---------------------------------------------------------------------------
// bn1: block per image. h = bn1(p1) + hp0 (both NHWC) in LDS; emits
// s1 NCHW-packed (for conv2m) and hp1 NCHW [n][c][9] (for FC).
// s1 image stride = 416 WORDS (32 ch x 13 words).
// ---------------------------------------------------------------------------
__global__ __launch_bounds__(256) void k_bn1(const float* __restrict__ p1,
                                             const float* __restrict__ hp0,
                                             const float* __restrict__ ss,
                                             uint32_t* __restrict__ s1,
                                             float* __restrict__ hp1) {
    __shared__ float H[1568];
    int n = blockIdx.x, t = threadIdx.x;
    const float* P = p1 + (size_t)n * 1568;
    const float* Hp = hp0 + (size_t)n * 1568;
    for (int i = t; i < 1568; i += 256) {
        int c = i & 31;
        H[i] = fmaf(ss[64 + c], P[i], ss[96 + c]) + Hp[i];
    }
    __syncthreads();
    if (t < 32) {
        int c = t;
        uint32_t* sp = s1 + (size_t)n * 416 + c * 13;
        for (int j = 0; j < 13; ++j) {
            uint32_t u = 0;
            #pragma unroll
            for (int k = 0; k < 4; ++k) {
                int f = 4 * j + k;
                int sv = (f < 49) ? sgn8(H[f * 32 + c]) : 0;
                u |= ((uint32_t)(uint8_t)(int8_t)sv) << (8 * k);
            }
            sp[j] = u;
        }
    }
    for (int jj = t; jj < 288; jj += 256) {
        int c = jj / 9, pix = jj - c * 9;
        int r = pix / 3, qq = pix - r * 3;
        float a0 = H[((2 * r) * 7 + 2 * qq) * 32 + c];
        float a1 = H[((2 * r) * 7 + 2 * qq + 1) * 32 + c];
        float a2 = H[((2 * r + 1) * 7 + 2 * qq) * 32 + c];
        float a3 = H[((2 * r + 1) * 7 + 2 * qq + 1) * 32 + c];
        hp1[n * 288 + c * 9 + pix] = fmaxf(fmaxf(a0, a1), fmaxf(a2, a3));
    }
}

// ---------------------------------------------------------------------------
// conv2 via bf16 MFMA implicit GEMM + fused stats. 8 images/block.
// part2 layout [c*512+b] / +32*512 for sq. p2 NCHW [n][32][9].
// ---------------------------------------------------------------------------
__global__ __launch_bounds__(256) void k_conv2m(const uint32_t* __restrict__ s1,
                                                const uint16_t* __restrict__ w2f,
                                                float* __restrict__ p2,
                                                double* __restrict__ part2) {
    __shared__ uint32_t lds[8192];   // 32 KB
    int t = threadIdx.x;
    int n0 = blockIdx.x * 8;
    for (int i = t; i < 120; i += 256) {
        int img = i / 15, e = i - img * 15;
        int p = (e < 8) ? e : (e - 7) * 8;
        uint32_t* d = &lds[img * 1024 + p * 16];
        uint4 z; z.x = z.y = z.z = z.w = 0u;
        ((uint4*)d)[0] = z; ((uint4*)d)[1] = z; ((uint4*)d)[2] = z; ((uint4*)d)[3] = z;
    }
    int lane = t & 63, wv = t >> 6;
    int q = lane >> 5, ncol = lane & 31;
    v8s wfr[18];
    #pragma unroll
    for (int f = 0; f < 18; ++f)
        wfr[f] = *(const v8s*)(w2f + (f * 2 + q) * 256 + ncol * 8);
    for (int i = t; i < 1664; i += 256) {
        int img = i / 208, r = i - img * 208;
        int c2 = r / 13, j = r - c2 * 13;
        const uint32_t* sb = s1 + (size_t)(n0 + img) * 416;
        uint32_t wa = sb[(2 * c2) * 13 + j];
        uint32_t wb = sb[(2 * c2 + 1) * 13 + j];
        int g = c2 >> 2, sub = c2 & 3;
        #pragma unroll
        for (int k = 0; k < 4; ++k) {
            int f = 4 * j + k;
            if (f < 49) {
                int y = f / 7, x = f - y * 7;
                int p = (y + 1) * 8 + (x + 1);
                uint32_t ba = (wa >> (8 * k)) & 0xFF;
                uint32_t bb = (wb >> (8 * k)) & 0xFF;
                uint32_t ha = ba ? (0x3F80u | ((ba & 0x80u) << 8)) : 0u;
                uint32_t hb = bb ? (0x3F80u | ((bb & 0x80u) << 8)) : 0u;
                lds[img * 1024 + p * 16 + ((g ^ (p & 3)) << 2) + sub] = ha | (hb << 16);
            }
        }
    }
    __syncthreads();
    int m = lane & 31;
    int quad = m & 3, pwl = m >> 2;
    int dy = quad >> 1, dx = quad & 1;
    double sAcc = 0.0, qAcc = 0.0;
    for (int tile = wv; tile < 9; tile += 4) {
        int pwg = tile * 8 + pwl;                    // 0..71
        int img = pwg / 9, pwi = pwg - img * 9;
        int py = pwi / 3, px = pwi - py * 3;
        int pbase = (2 * py + dy) * 8 + 2 * px + dx;
        v16f acc;
        #pragma unroll
        for (int i = 0; i < 16; ++i) acc[i] = 0.f;
        #pragma unroll
        for (int tp = 0; tp < 9; ++tp) {
            int p = pbase + (tp / 3) * 8 + (tp % 3);
            int psw = p & 3;
            #pragma unroll
            for (int kh = 0; kh < 2; ++kh) {
                int g = kh * 2 + q;
                int idx = img * 1024 + p * 16 + ((g ^ psw) << 2);
                v8s a = *(const v8s*)&lds[idx];
                acc = __builtin_amdgcn_mfma_f32_32x32x16_bf16(a, wfr[tp * 2 + kh], acc, 0, 0, 0);
            }
        }
        #pragma unroll
        for (int g4 = 0; g4 < 4; ++g4) {
            float mx = fmaxf(fmaxf(acc[4 * g4], acc[4 * g4 + 1]),
                             fmaxf(acc[4 * g4 + 2], acc[4 * g4 + 3]));
            int pwo = tile * 8 + 2 * g4 + q;          // 0..71
            int oimg = pwo / 9, opwi = pwo - oimg * 9;
            p2[(size_t)(n0 + oimg) * 288 + ncol * 9 + opwi] = mx;
            double v = (double)mx;
            sAcc += v; qAcc += v * v;
        }
    }
    __syncthreads();
    double* red = (double*)lds;   // act LDS dead; 512 doubles
    red[(wv * 2 + q) * 32 + ncol] = sAcc;
    red[256 + (wv * 2 + q) * 32 + ncol] = qAcc;
    __syncthreads();
    if (t < 32) {
        double S = 0.0, Q = 0.0;
        #pragma unroll
        for (int i = 0; i < 8; ++i) { S += red[i * 32 + t]; Q += red[256 + i * 32 + t]; }
        part2[(size_t)t * 512 + blockIdx.x] = S;
        part2[(size_t)32 * 512 + (size_t)t * 512 + blockIdx.x] = Q;
    }
}

// ---------------------------------------------------------------------------
// FC: out[n,k] = sum_j (bn2(p2)+hp1)[n,j] * fw[k,j] + fb[k].  Wave per image.
// ---------------------------------------------------------------------------
__global__ __launch_bounds__(256) void k_fc(const float* __restrict__ p2,
                                            const float* __restrict__ hp1,
                                            const float* __restrict__ ss,
                                            const float* __restrict__ fw,
                                            const float* __restrict__ fb,
                                            float* __restrict__ outv) {
    int wv = threadIdx.x >> 6, l = threadIdx.x & 63;
    int n = blockIdx.x * 4 + wv;
    float acc[10];
    #pragma unroll
    for (int k = 0; k < 10; ++k) acc[k] = 0.f;
    #pragma unroll
    for (int i = 0; i < 5; ++i) {
        int j = l + 64 * i;
        if (j < 288) {
            int c = j / 9;
            float h = fmaf(ss[128 + c], p2[n * 288 + j], ss[160 + c]) + hp1[n * 288 + j];
            #pragma unroll
            for (int k = 0; k < 10; ++k)
                acc[k] = fmaf(h, fw[k * 288 + j], acc[k]);
        }
    }
    #pragma unroll
    for (int k = 0; k < 10; ++k) {
        float s = acc[k];
        #pragma unroll
        for (int o = 32; o > 0; o >>= 1) s += __shfl_down(s, o);
        if (l == 0) outv[n * 10 + k] = s + fb[k];
    }
}

// ---------------------------------------------------------------------------
// Workspace layout (bytes), ~154.2 MB.
//   ss   @1024  768 | w1f @2048 18432(bf16) | w2f @38912 18432(bf16)
//   p0 (NHWC) @76800 102760448 | p1(NHWC) @76800 25690112
//   s1   @25766912 (416 words/img) | hp1 @32582656 | p2 @37301248
//   part1 @60000000 512KB  (dead mid-p0 zone during conv1m->finalize1)
//   s0(NHWC int8) @102837248 25690112
//     part0 (2 MB, conv0->finalize0, before bn0 writes s0) aliases its head
//     part2 (256 KB, conv2m->finalize2, s0 long dead) aliases its head
//   hp0(NHWC) @128527360 25690112
// ---------------------------------------------------------------------------
extern "C" void kernel_launch(void* const* d_in, const int* in_sizes, int n_in,
                              void* d_out, int out_size, void* d_ws, size_t ws_size,
                              hipStream_t stream) {
    (void)in_sizes; (void)n_in; (void)out_size; (void)ws_size;
    const float* x  = (const float*)d_in[0];
    const float* w0 = (const float*)d_in[1];
    const float* g0 = (const float*)d_in[2];
    const float* b0 = (const float*)d_in[3];
    const float* w1 = (const float*)d_in[4];
    const float* g1 = (const float*)d_in[5];
    const float* b1 = (const float*)d_in[6];
    const float* w2 = (const float*)d_in[7];
    const float* g2 = (const float*)d_in[8];
    const float* b2 = (const float*)d_in[9];
    const float* fw = (const float*)d_in[10];
    const float* fb = (const float*)d_in[11];
    float* outv = (float*)d_out;
    char* ws = (char*)d_ws;

    float*     ss    = (float*)(ws + 1024);
    uint16_t*  w1f   = (uint16_t*)(ws + 2048);
    uint16_t*  w2f   = (uint16_t*)(ws + 38912);
    float*     p0    = (float*)(ws + 76800);
    float*     p1    = (float*)(ws + 76800);
    uint32_t*  s1    = (uint32_t*)(ws + 25766912);
    float*     hp1   = (float*)(ws + 32582656);
    float*     p2    = (float*)(ws + 37301248);
    double*    part1 = (double*)(ws + 60000000);
    int8_t*    s0    = (int8_t*)(ws + 102837248);
    double*    part0 = (double*)(ws + 102837248);
    double*    part2 = (double*)(ws + 102837248);
    float*     hp0   = (float*)(ws + 128527360);

    k_signw1<<<36, 256, 0, stream>>>(w1, w1f);
    k_signw1<<<36, 256, 0, stream>>>(w2, w2f);

    k_conv0<<<BATCH, 448, 0, stream>>>(x, w0, p0, part0);
    k_finalize<<<32, 256, 0, stream>>>(part0, 4096, g0, b0, 1.0 / (BATCH * 196.0), ss);
    k_bn0<<<BATCH, 256, 0, stream>>>(p0, ss, s0, hp0);

    k_conv1m<<<BATCH / 4, 256, 0, stream>>>(s0, w1f, p1, part1);
    k_finalize<<<32, 256, 0, stream>>>(part1, 1024, g1, b1, 1.0 / (BATCH * 49.0), ss + 64);
    k_bn1<<<BATCH, 256, 0, stream>>>(p1, hp0, ss, s1, hp1);

    k_conv2m<<<BATCH / 8, 256, 0, stream>>>(s1, w2f, p2, part2);
    k_finalize<<<32, 256, 0, stream>>>(part2, 512, g2, b2, 1.0 / (BATCH * 9.0), ss + 128);

    k_fc<<<BATCH / 4, 256, 0, stream>>>(p2, hp1, ss, fw, fb, outv);
}

// Round 11
// 217.940 us; speedup vs baseline: 1.2948x; 1.0234x over previous
//
#include <hip/hip_runtime.h>
#include <stdint.h>

#define BATCH 4096

typedef float v16f __attribute__((ext_vector_type(16)));
typedef short v8s  __attribute__((ext_vector_type(8)));

__device__ __forceinline__ int sgn8(float v) {
    return (v > 0.f) ? 1 : ((v < 0.f) ? -1 : 0);
}

// ---------------------------------------------------------------------------
// sign(w) -> bf16 MFMA B-fragment layout (used for BOTH w1 and w2):
// o[tp*1024 + kh*512 + q*256 + n*8 + j] = sign(w[n][kh*16+q*8+j][tp]) as bf16
// ---------------------------------------------------------------------------
__global__ void k_signw1(const float* __restrict__ w, uint16_t* __restrict__ o) {
    int i = blockIdx.x * 256 + threadIdx.x;
    if (i >= 9216) return;
    int j = i & 7, n = (i >> 3) & 31, q = (i >> 8) & 1, kh = (i >> 9) & 1, tp = i >> 10;
    int cin = kh * 16 + q * 8 + j;
    float v = w[(n * 32 + cin) * 9 + tp];
    o[i] = (v > 0.f) ? 0x3F80 : ((v < 0.f) ? 0xBF80 : 0);
}

// ---------------------------------------------------------------------------
// conv0s: STATS-ONLY conv0 (no p0 store). fp32 conv 3x3 pad1 + pool ->
// per-channel double stats. 448 threads, c=t&31, py=t>>5; sliding float4.
// part0 layout [c*4096+n] (+32*4096 sq). FMA order is the canonical conv0
// order -- k_bn0r recomputes the SAME sequence bit-identically.
// ---------------------------------------------------------------------------
__global__ __launch_bounds__(448) void k_conv0s(const float* __restrict__ x,
                                                const float* __restrict__ w0,
                                                double* __restrict__ part0) {
    __shared__ float xs[960];   // 30 rows x 32 cols (zero halo)
    __shared__ float wl[288];
    __shared__ double rs[32][14], rq[32][14];
    int n = blockIdx.x, t = threadIdx.x;
    for (int i = t; i < 960; i += 448) xs[i] = 0.f;
    for (int i = t; i < 288; i += 448) wl[i] = w0[i];
    __syncthreads();
    for (int i = t; i < 784; i += 448) {
        int y = i / 28, xx = i - y * 28;
        xs[(y + 1) * 32 + xx + 1] = x[n * 784 + i];
    }
    __syncthreads();
    int c = t & 31, py = t >> 5;
    float wreg[9];
    #pragma unroll
    for (int i = 0; i < 9; ++i) wreg[i] = wl[c * 9 + i];
    const float4* X4 = (const float4*)xs;
    float4 cur0 = X4[(2 * py + 0) * 8];
    float4 cur1 = X4[(2 * py + 1) * 8];
    float4 cur2 = X4[(2 * py + 2) * 8];
    float4 cur3 = X4[(2 * py + 3) * 8];
    double s = 0.0, q = 0.0;
    #pragma unroll
    for (int k = 0; k < 7; ++k) {
        float4 n0 = X4[(2 * py + 0) * 8 + k + 1];
        float4 n1 = X4[(2 * py + 1) * 8 + k + 1];
        float4 n2 = X4[(2 * py + 2) * 8 + k + 1];
        float4 n3 = X4[(2 * py + 3) * 8 + k + 1];
        float a[4][6];
        a[0][0] = cur0.x; a[0][1] = cur0.y; a[0][2] = cur0.z; a[0][3] = cur0.w; a[0][4] = n0.x; a[0][5] = n0.y;
        a[1][0] = cur1.x; a[1][1] = cur1.y; a[1][2] = cur1.z; a[1][3] = cur1.w; a[1][4] = n1.x; a[1][5] = n1.y;
        a[2][0] = cur2.x; a[2][1] = cur2.y; a[2][2] = cur2.z; a[2][3] = cur2.w; a[2][4] = n2.x; a[2][5] = n2.y;
        a[3][0] = cur3.x; a[3][1] = cur3.y; a[3][2] = cur3.z; a[3][3] = cur3.w; a[3][4] = n3.x; a[3][5] = n3.y;
        #pragma unroll
        for (int e = 0; e < 2; ++e) {
            int base = 2 * e;
            float s00 = 0.f, s01 = 0.f, s10 = 0.f, s11 = 0.f;
            #pragma unroll
            for (int ky = 0; ky < 3; ++ky)
            #pragma unroll
            for (int kx = 0; kx < 3; ++kx) {
                float w = wreg[ky * 3 + kx];
                s00 = fmaf(a[ky][base + kx], w, s00);
                s01 = fmaf(a[ky][base + kx + 1], w, s01);
                s10 = fmaf(a[ky + 1][base + kx], w, s10);
                s11 = fmaf(a[ky + 1][base + kx + 1], w, s11);
            }
            float m = fmaxf(fmaxf(s00, s01), fmaxf(s10, s11));
            double v = (double)m;
            s += v; q += v * v;
        }
        cur0 = n0; cur1 = n1; cur2 = n2; cur3 = n3;
    }
    rs[c][py] = s; rq[c][py] = q;
    __syncthreads();
    if (t < 32) {
        double S = 0.0, Q = 0.0;
        #pragma unroll
        for (int i = 0; i < 14; ++i) { S += rs[t][i]; Q += rq[t][i]; }
        part0[(size_t)t * 4096 + n] = S;
        part0[(size_t)32 * 4096 + (size_t)t * 4096 + n] = Q;
    }
}

// ---------------------------------------------------------------------------
// finalize: grid(32) x 256 threads. Block = channel. Fixed-order reduction
// of G partials, layout part[c*G+i] / part[32G+c*G+i]; coalesced; double.
// ---------------------------------------------------------------------------
__global__ __launch_bounds__(256) void k_finalize(const double* __restrict__ part, int G,
                                                  const float* __restrict__ g,
                                                  const float* __restrict__ b,
                                                  double inv_count, float* __restrict__ ss) {
    int c = blockIdx.x, t = threadIdx.x;
    double s = 0.0, q = 0.0;
    for (int i = t; i < G; i += 256) {
        s += part[(size_t)c * G + i];
        q += part[(size_t)32 * G + (size_t)c * G + i];
    }
    #pragma unroll
    for (int o = 32; o > 0; o >>= 1) { s += __shfl_down(s, o); q += __shfl_down(q, o); }
    __shared__ double rs[4], rq[4];
    int w = t >> 6, l = t & 63;
    if (l == 0) { rs[w] = s; rq[w] = q; }
    __syncthreads();
    if (t == 0) {
        s = rs[0] + rs[1] + rs[2] + rs[3];
        q = rq[0] + rq[1] + rq[2] + rq[3];
        double mean = s * inv_count;
        double var = q * inv_count - mean * mean;
        double sc = (double)g[c] / sqrt(var + 1e-5);
        ss[c] = (float)sc;
        ss[32 + c] = (float)((double)b[c] - mean * sc);
    }
}

// ---------------------------------------------------------------------------
// bn0r: RECOMPUTES conv0 (bit-identical FMA order), applies BN, and emits:
//  - s0b: conv1m's exact LDS image format -- bf16 signs, 16x16 halo grid,
//    64B/pixel, quad swizzle qd = g ^ psw with psw = (x&3)^(y&3), halo
//    pre-zeroed. 16 KB per image.
//  - hp0: NHWC fp32 [n][49][32] (pool of BN'd h).
// 448 threads; h staged in LDS P[196][33].
// ---------------------------------------------------------------------------
__global__ __launch_bounds__(448) void k_bn0r(const float* __restrict__ x,
                                              const float* __restrict__ w0,
                                              const float* __restrict__ ss,
                                              uint32_t* __restrict__ s0b,
                                              float* __restrict__ hp0) {
    __shared__ float xs[960];
    __shared__ float wl[288];
    __shared__ float P[6468];   // 196 x 33
    int n = blockIdx.x, t = threadIdx.x;
    for (int i = t; i < 960; i += 448) xs[i] = 0.f;
    for (int i = t; i < 288; i += 448) wl[i] = w0[i];
    __syncthreads();
    for (int i = t; i < 784; i += 448) {
        int y = i / 28, xx = i - y * 28;
        xs[(y + 1) * 32 + xx + 1] = x[n * 784 + i];
    }
    __syncthreads();
    int c = t & 31, py = t >> 5;
    float wreg[9];
    #pragma unroll
    for (int i = 0; i < 9; ++i) wreg[i] = wl[c * 9 + i];
    float sc = ss[c], sh = ss[32 + c];
    const float4* X4 = (const float4*)xs;
    float4 cur0 = X4[(2 * py + 0) * 8];
    float4 cur1 = X4[(2 * py + 1) * 8];
    float4 cur2 = X4[(2 * py + 2) * 8];
    float4 cur3 = X4[(2 * py + 3) * 8];
    #pragma unroll
    for (int k = 0; k < 7; ++k) {
        float4 n0 = X4[(2 * py + 0) * 8 + k + 1];
        float4 n1 = X4[(2 * py + 1) * 8 + k + 1];
        float4 n2 = X4[(2 * py + 2) * 8 + k + 1];
        float4 n3 = X4[(2 * py + 3) * 8 + k + 1];
        float a[4][6];
        a[0][0] = cur0.x; a[0][1] = cur0.y; a[0][2] = cur0.z; a[0][3] = cur0.w; a[0][4] = n0.x; a[0][5] = n0.y;
        a[1][0] = cur1.x; a[1][1] = cur1.y; a[1][2] = cur1.z; a[1][3] = cur1.w; a[1][4] = n1.x; a[1][5] = n1.y;
        a[2][0] = cur2.x; a[2][1] = cur2.y; a[2][2] = cur2.z; a[2][3] = cur2.w; a[2][4] = n2.x; a[2][5] = n2.y;
        a[3][0] = cur3.x; a[3][1] = cur3.y; a[3][2] = cur3.z; a[3][3] = cur3.w; a[3][4] = n3.x; a[3][5] = n3.y;
        #pragma unroll
        for (int e = 0; e < 2; ++e) {
            int base = 2 * e;
            float s00 = 0.f, s01 = 0.f, s10 = 0.f, s11 = 0.f;
            #pragma unroll
            for (int ky = 0; ky < 3; ++ky)
            #pragma unroll
            for (int kx = 0; kx < 3; ++kx) {
                float w = wreg[ky * 3 + kx];
                s00 = fmaf(a[ky][base + kx], w, s00);
                s01 = fmaf(a[ky][base + kx + 1], w, s01);
                s10 = fmaf(a[ky + 1][base + kx], w, s10);
                s11 = fmaf(a[ky + 1][base + kx + 1], w, s11);
            }
            float m = fmaxf(fmaxf(s00, s01), fmaxf(s10, s11));
            P[(py * 14 + 2 * k + e) * 33 + c] = fmaf(sc, m, sh);
        }
        cur0 = n0; cur1 = n1; cur2 = n2; cur3 = n3;
    }
    __syncthreads();
    uint32_t* simg = s0b + (size_t)n * 4096;
    // interior: 196 pixels x 4 quads
    for (int i = t; i < 784; i += 448) {
        int pl = i >> 2, qd = i & 3;
        int iy = pl / 14, ix = pl - iy * 14;
        int yy = iy + 1, xx2 = ix + 1;
        int p = yy * 16 + xx2;
        int psw = (xx2 & 3) ^ (yy & 3);
        int g = qd ^ psw;
        const float* Pp = &P[pl * 33 + g * 8];
        uint32_t d[4];
        #pragma unroll
        for (int j = 0; j < 4; ++j) {
            float h0 = Pp[2 * j], h1 = Pp[2 * j + 1];
            uint32_t b0 = (h0 > 0.f) ? 0x3F80u : ((h0 < 0.f) ? 0xBF80u : 0u);
            uint32_t b1 = (h1 > 0.f) ? 0x3F80u : ((h1 < 0.f) ? 0xBF80u : 0u);
            d[j] = b0 | (b1 << 16);
        }
        uint4 v; v.x = d[0]; v.y = d[1]; v.z = d[2]; v.w = d[3];
        *(uint4*)(simg + p * 16 + qd * 4) = v;
    }
    // halo: 60 border pixels x 4 quads, zero
    if (t < 240) {
        int e = t >> 2, qd = t & 3;
        int yh, xh;
        if (e < 16)      { yh = 0;      xh = e; }
        else if (e < 32) { yh = 15;     xh = e - 16; }
        else if (e < 46) { yh = e - 31; xh = 0; }
        else             { yh = e - 45; xh = 15; }
        uint4 z; z.x = z.y = z.z = z.w = 0u;
        *(uint4*)(simg + (yh * 16 + xh) * 16 + qd * 4) = z;
    }
    // hp0: 2x2 maxpool of h
    if (t < 196) {
        int pw = t >> 2, oct = t & 3;
        int pyy = pw / 7, pxx = pw - pyy * 7;
        int b00 = ((2 * pyy) * 14 + 2 * pxx) * 33;
        int b01 = b00 + 33;
        int b10 = b00 + 14 * 33;
        int b11 = b10 + 33;
        float out[8];
        #pragma unroll
        for (int k = 0; k < 8; ++k) {
            int cc = oct * 8 + k;
            out[k] = fmaxf(fmaxf(P[b00 + cc], P[b01 + cc]),
                           fmaxf(P[b10 + cc], P[b11 + cc]));
        }
        float4* hd = (float4*)(hp0 + ((size_t)n * 49 + pw) * 32 + oct * 8);
        float4 h0; h0.x = out[0]; h0.y = out[1]; h0.z = out[2]; h0.w = out[3];
        float4 h1; h1.x = out[4]; h1.y = out[5]; h1.z = out[6]; h1.w = out[7];
        hd[0] = h0; hd[1] = h1;
    }
}

// ---------------------------------------------------------------------------
// conv1m: bf16 MFMA implicit GEMM. 2 images/block (32 KB LDS), staging is a
// flat uint4 copy of bn0r's pre-swizzled image blocks. Swizzle
// psw=(x&3)^(y&3)=((p^(p>>4))&3) spreads bank quads (4-way vs old 8-way).
// Wave wv: image wv>>1, tiles (wv&1), +2, ... Fused stats, G=2048,
// part layout [c*2048+b] / +32*2048.
// ---------------------------------------------------------------------------
__global__ __launch_bounds__(256) void k_conv1m(const uint32_t* __restrict__ s0b,
                                                const uint16_t* __restrict__ w1f,
                                                float* __restrict__ p1,
                                                double* __restrict__ part1) {
    __shared__ uint32_t lds[8192];   // 32 KB: 2 images x 4096 dwords
    int t = threadIdx.x;
    int n0 = blockIdx.x * 2;
    const uint4* gp = (const uint4*)(s0b + (size_t)n0 * 4096);
    uint4* lp = (uint4*)lds;
    #pragma unroll
    for (int i = 0; i < 8; ++i) lp[t + i * 256] = gp[t + i * 256];
    int lane = t & 63, wv = t >> 6;
    int q = lane >> 5, ncol = lane & 31;
    v8s wfr[18];
    #pragma unroll
    for (int f = 0; f < 18; ++f)
        wfr[f] = *(const v8s*)(w1f + (f * 2 + q) * 256 + ncol * 8);
    __syncthreads();
    int img = wv >> 1, wh = wv & 1;
    int n = n0 + img;
    int ibase = img * 4096;
    int m = lane & 31;
    int quad = m & 3, pwl = m >> 2;
    int dy = quad >> 1, dx = quad & 1;
    double sAcc = 0.0, qAcc = 0.0;
    for (int tile = wh; tile < 7; tile += 2) {
        int pw = tile * 8 + pwl;
        int pwc = min(pw, 48);
        int py = pwc / 7, px = pwc - py * 7;
        int pbase = (2 * py + dy) * 16 + 2 * px + dx;
        v16f acc;
        #pragma unroll
        for (int i = 0; i < 16; ++i) acc[i] = 0.f;
        #pragma unroll
        for (int tp = 0; tp < 9; ++tp) {
            int p = pbase + (tp / 3) * 16 + (tp % 3);
            int psw = (p ^ (p >> 4)) & 3;
            #pragma unroll
            for (int kh = 0; kh < 2; ++kh) {
                int g = kh * 2 + q;
                int idx = ibase + p * 16 + ((g ^ psw) << 2);
                v8s a = *(const v8s*)&lds[idx];
                acc = __builtin_amdgcn_mfma_f32_32x32x16_bf16(a, wfr[tp * 2 + kh], acc, 0, 0, 0);
            }
        }
        #pragma unroll
        for (int g4 = 0; g4 < 4; ++g4) {
            float mx = fmaxf(fmaxf(acc[4 * g4], acc[4 * g4 + 1]),
                             fmaxf(acc[4 * g4 + 2], acc[4 * g4 + 3]));
            int pwo = tile * 8 + 2 * g4 + q;
            if (pwo < 49) {
                p1[((size_t)n * 49 + pwo) * 32 + ncol] = mx;
                double v = (double)mx;
                sAcc += v; qAcc += v * v;
            }
        }
    }
    __syncthreads();
    double* red = (double*)lds;   // act LDS dead; 512 doubles
    red[(wv * 2 + q) * 32 + ncol] = sAcc;
    red[256 + (wv * 2 + q) * 32 + ncol] = qAcc;
    __syncthreads();
    if (t < 32) {
        double S = 0.0, Q = 0.0;
        #pragma unroll
        for (int i = 0; i < 8; ++i) { S += red[i * 32 + t]; Q += red[256 + i * 32 + t]; }
        part1[(size_t)t * 2048 + blockIdx.x] = S;
        part1[(size_t)32 * 2048 + (size_t)t * 2048 + blockIdx.x] = Q;
    }
}

// ---------------------------------------------------------------------------
// bn1: block per image. h = bn1(p1) + hp0 (both NHWC) in LDS; emits
// s1 NCHW-packed (for conv2m) and hp1 NCHW [n][c][9] (for FC).
// s1 image stride = 416 WORDS (32 ch x 13 words).
// ---------------------------------------------------------------------------
__global__ __launch_bounds__(256) void k_bn1(const float* __restrict__ p1,
                                             const float* __restrict__ hp0,
                                             const float* __restrict__ ss,
                                             uint32_t* __restrict__ s1,
                                             float* __restrict__ hp1) {
    __shared__ float H[1568];
    int n = blockIdx.x, t = threadIdx.x;
    const float* P = p1 + (size_t)n * 1568;
    const float* Hp = hp0 + (size_t)n * 1568;
    for (int i = t; i < 1568; i += 256) {
        int c = i & 31;
        H[i] = fmaf(ss[64 + c], P[i], ss[96 + c]) + Hp[i];
    }
    __syncthreads();
    if (t < 32) {
        int c = t;
        uint32_t* sp = s1 + (size_t)n * 416 + c * 13;
        for (int j = 0; j < 13; ++j) {
            uint32_t u = 0;
            #pragma unroll
            for (int k = 0; k < 4; ++k) {
                int f = 4 * j + k;
                int sv = (f < 49) ? sgn8(H[f * 32 + c]) : 0;
                u |= ((uint32_t)(uint8_t)(int8_t)sv) << (8 * k);
            }
            sp[j] = u;
        }
    }
    for (int jj = t; jj < 288; jj += 256) {
        int c = jj / 9, pix = jj - c * 9;
        int r = pix / 3, qq = pix - r * 3;
        float a0 = H[((2 * r) * 7 + 2 * qq) * 32 + c];
        float a1 = H[((2 * r) * 7 + 2 * qq + 1) * 32 + c];
        float a2 = H[((2 * r + 1) * 7 + 2 * qq) * 32 + c];
        float a3 = H[((2 * r + 1) * 7 + 2 * qq + 1) * 32 + c];
        hp1[n * 288 + c * 9 + pix] = fmaxf(fmaxf(a0, a1), fmaxf(a2, a3));
    }
}

// ---------------------------------------------------------------------------
// conv2 via bf16 MFMA implicit GEMM + fused stats. 8 images/block.
// part2 layout [c*512+b] / +32*512 for sq. p2 NCHW [n][32][9].
// ---------------------------------------------------------------------------
__global__ __launch_bounds__(256) void k_conv2m(const uint32_t* __restrict__ s1,
                                                const uint16_t* __restrict__ w2f,
                                                float* __restrict__ p2,
                                                double* __restrict__ part2) {
    __shared__ uint32_t lds[8192];   // 32 KB
    int t = threadIdx.x;
    int n0 = blockIdx.x * 8;
    for (int i = t; i < 120; i += 256) {
        int img = i / 15, e = i - img * 15;
        int p = (e < 8) ? e : (e - 7) * 8;
        uint32_t* d = &lds[img * 1024 + p * 16];
        uint4 z; z.x = z.y = z.z = z.w = 0u;
        ((uint4*)d)[0] = z; ((uint4*)d)[1] = z; ((uint4*)d)[2] = z; ((uint4*)d)[3] = z;
    }
    int lane = t & 63, wv = t >> 6;
    int q = lane >> 5, ncol = lane & 31;
    v8s wfr[18];
    #pragma unroll
    for (int f = 0; f < 18; ++f)
        wfr[f] = *(const v8s*)(w2f + (f * 2 + q) * 256 + ncol * 8);
    for (int i = t; i < 1664; i += 256) {
        int img = i / 208, r = i - img * 208;
        int c2 = r / 13, j = r - c2 * 13;
        const uint32_t* sb = s1 + (size_t)(n0 + img) * 416;
        uint32_t wa = sb[(2 * c2) * 13 + j];
        uint32_t wb = sb[(2 * c2 + 1) * 13 + j];
        int g = c2 >> 2, sub = c2 & 3;
        #pragma unroll
        for (int k = 0; k < 4; ++k) {
            int f = 4 * j + k;
            if (f < 49) {
                int y = f / 7, x = f - y * 7;
                int p = (y + 1) * 8 + (x + 1);
                uint32_t ba = (wa >> (8 * k)) & 0xFF;
                uint32_t bb = (wb >> (8 * k)) & 0xFF;
                uint32_t ha = ba ? (0x3F80u | ((ba & 0x80u) << 8)) : 0u;
                uint32_t hb = bb ? (0x3F80u | ((bb & 0x80u) << 8)) : 0u;
                lds[img * 1024 + p * 16 + ((g ^ (p & 3)) << 2) + sub] = ha | (hb << 16);
            }
        }
    }
    __syncthreads();
    int m = lane & 31;
    int quad = m & 3, pwl = m >> 2;
    int dy = quad >> 1, dx = quad & 1;
    double sAcc = 0.0, qAcc = 0.0;
    for (int tile = wv; tile < 9; tile += 4) {
        int pwg = tile * 8 + pwl;                    // 0..71
        int img = pwg / 9, pwi = pwg - img * 9;
        int py = pwi / 3, px = pwi - py * 3;
        int pbase = (2 * py + dy) * 8 + 2 * px + dx;
        v16f acc;
        #pragma unroll
        for (int i = 0; i < 16; ++i) acc[i] = 0.f;
        #pragma unroll
        for (int tp = 0; tp < 9; ++tp) {
            int p = pbase + (tp / 3) * 8 + (tp % 3);
            int psw = p & 3;
            #pragma unroll
            for (int kh = 0; kh < 2; ++kh) {
                int g = kh * 2 + q;
                int idx = img * 1024 + p * 16 + ((g ^ psw) << 2);
                v8s a = *(const v8s*)&lds[idx];
                acc = __builtin_amdgcn_mfma_f32_32x32x16_bf16(a, wfr[tp * 2 + kh], acc, 0, 0, 0);
            }
        }
        #pragma unroll
        for (int g4 = 0; g4 < 4; ++g4) {
            float mx = fmaxf(fmaxf(acc[4 * g4], acc[4 * g4 + 1]),
                             fmaxf(acc[4 * g4 + 2], acc[4 * g4 + 3]));
            int pwo = tile * 8 + 2 * g4 + q;          // 0..71
            int oimg = pwo / 9, opwi = pwo - oimg * 9;
            p2[(size_t)(n0 + oimg) * 288 + ncol * 9 + opwi] = mx;
            double v = (double)mx;
            sAcc += v; qAcc += v * v;
        }
    }
    __syncthreads();
    double* red = (double*)lds;   // act LDS dead; 512 doubles
    red[(wv * 2 + q) * 32 + ncol] = sAcc;
    red[256 + (wv * 2 + q) * 32 + ncol] = qAcc;
    __syncthreads();
    if (t < 32) {
        double S = 0.0, Q = 0.0;
        #pragma unroll
        for (int i = 0; i < 8; ++i) { S += red[i * 32 + t]; Q += red[256 + i * 32 + t]; }
        part2[(size_t)t * 512 + blockIdx.x] = S;
        part2[(size_t)32 * 512 + (size_t)t * 512 + blockIdx.x] = Q;
    }
}

// ---------------------------------------------------------------------------
// FC: out[n,k] = sum_j (bn2(p2)+hp1)[n,j] * fw[k,j] + fb[k].  Wave per image.
// ---------------------------------------------------------------------------
__global__ __launch_bounds__(256) void k_fc(const float* __restrict__ p2,
                                            const float* __restrict__ hp1,
                                            const float* __restrict__ ss,
                                            const float* __restrict__ fw,
                                            const float* __restrict__ fb,
                                            float* __restrict__ outv) {
    int wv = threadIdx.x >> 6, l = threadIdx.x & 63;
    int n = blockIdx.x * 4 + wv;
    float acc[10];
    #pragma unroll
    for (int k = 0; k < 10; ++k) acc[k] = 0.f;
    #pragma unroll
    for (int i = 0; i < 5; ++i) {
        int j = l + 64 * i;
        if (j < 288) {
            int c = j / 9;
            float h = fmaf(ss[128 + c], p2[n * 288 + j], ss[160 + c]) + hp1[n * 288 + j];
            #pragma unroll
            for (int k = 0; k < 10; ++k)
                acc[k] = fmaf(h, fw[k * 288 + j], acc[k]);
        }
    }
    #pragma unroll
    for (int k = 0; k < 10; ++k) {
        float s = acc[k];
        #pragma unroll
        for (int o = 32; o > 0; o >>= 1) s += __shfl_down(s, o);
        if (l == 0) outv[n * 10 + k] = s + fb[k];
    }
}

// ---------------------------------------------------------------------------
// Workspace layout (bytes), ~154.2 MB, NO aliasing (p0 eliminated):
//   ss    @1024       768
//   w1f   @2048       18432 | w2f @38912 18432
//   p1    @76800      25690112  (NHWC)
//   s1    @25766912   6815744
//   hp1   @32582656   4718592
//   p2    @37301248   4718592
//   s0b   @42019840   67108864  (bf16 pre-swizzled conv1 images, 16KB/img)
//   part0 @109128704  2097152
//   part1 @111225856  1048576
//   part2 @112274432  262144
//   hp0   @128527360  25690112  (end 154217472)
// ---------------------------------------------------------------------------
extern "C" void kernel_launch(void* const* d_in, const int* in_sizes, int n_in,
                              void* d_out, int out_size, void* d_ws, size_t ws_size,
                              hipStream_t stream) {
    (void)in_sizes; (void)n_in; (void)out_size; (void)ws_size;
    const float* x  = (const float*)d_in[0];
    const float* w0 = (const float*)d_in[1];
    const float* g0 = (const float*)d_in[2];
    const float* b0 = (const float*)d_in[3];
    const float* w1 = (const float*)d_in[4];
    const float* g1 = (const float*)d_in[5];
    const float* b1 = (const float*)d_in[6];
    const float* w2 = (const float*)d_in[7];
    const float* g2 = (const float*)d_in[8];
    const float* b2 = (const float*)d_in[9];
    const float* fw = (const float*)d_in[10];
    const float* fb = (const float*)d_in[11];
    float* outv = (float*)d_out;
    char* ws = (char*)d_ws;

    float*     ss    = (float*)(ws + 1024);
    uint16_t*  w1f   = (uint16_t*)(ws + 2048);
    uint16_t*  w2f   = (uint16_t*)(ws + 38912);
    float*     p1    = (float*)(ws + 76800);
    uint32_t*  s1    = (uint32_t*)(ws + 25766912);
    float*     hp1   = (float*)(ws + 32582656);
    float*     p2    = (float*)(ws + 37301248);
    uint32_t*  s0b   = (uint32_t*)(ws + 42019840);
    double*    part0 = (double*)(ws + 109128704);
    double*    part1 = (double*)(ws + 111225856);
    double*    part2 = (double*)(ws + 112274432);
    float*     hp0   = (float*)(ws + 128527360);

    k_signw1<<<36, 256, 0, stream>>>(w1, w1f);
    k_signw1<<<36, 256, 0, stream>>>(w2, w2f);

    k_conv0s<<<BATCH, 448, 0, stream>>>(x, w0, part0);
    k_finalize<<<32, 256, 0, stream>>>(part0, 4096, g0, b0, 1.0 / (BATCH * 196.0), ss);
    k_bn0r<<<BATCH, 448, 0, stream>>>(x, w0, ss, s0b, hp0);

    k_conv1m<<<BATCH / 2, 256, 0, stream>>>(s0b, w1f, p1, part1);
    k_finalize<<<32, 256, 0, stream>>>(part1, 2048, g1, b1, 1.0 / (BATCH * 49.0), ss + 64);
    k_bn1<<<BATCH, 256, 0, stream>>>(p1, hp0, ss, s1, hp1);

    k_conv2m<<<BATCH / 8, 256, 0, stream>>>(s1, w2f, p2, part2);
    k_finalize<<<32, 256, 0, stream>>>(part2, 512, g2, b2, 1.0 / (BATCH * 9.0), ss + 128);

    k_fc<<<BATCH / 4, 256, 0, stream>>>(p2, hp1, ss, fw, fb, outv);
}